// Round 6
// baseline (567.117 us; speedup 1.0000x reference)
//
#include <hip/hip_runtime.h>
#include <hip/hip_bf16.h>
#include <math.h>

#define NN   20000
#define NE   200000
#define NG   128
#define EMBD 256
#define NL   4
#define RBFD 10
#define RBFP 12   // padded rbf row stride (16B-aligned rows)
#define GSPL 8

typedef __attribute__((ext_vector_type(8))) short bf16x8;
typedef __attribute__((ext_vector_type(4))) float f32x4;
typedef __attribute__((ext_vector_type(2))) float f32x2;

__device__ __forceinline__ f32x4 unpk(uint2 u) {
  f32x4 r;
  r.x = __uint_as_float(u.x << 16);
  r.y = __uint_as_float(u.x & 0xffff0000u);
  r.z = __uint_as_float(u.y << 16);
  r.w = __uint_as_float(u.y & 0xffff0000u);
  return r;
}

// ---------------- prep kernels ----------------

__global__ void k_embed(const int* __restrict__ x, const float* __restrict__ emb,
                        float* __restrict__ xn, __hip_bfloat16* __restrict__ xnb) {
  int idx = blockIdx.x * blockDim.x + threadIdx.x;   // float4 index
  if (idx >= NN * (EMBD / 4)) return;
  int n  = idx >> 6;
  int c4 = (idx & 63) << 2;
  float4 v = *(const float4*)(emb + (size_t)x[n] * EMBD + c4);
  *(float4*)(xn + (size_t)n * EMBD + c4) = v;
  __hip_bfloat16* xb = xnb + (size_t)n * EMBD + c4;
  xb[0] = __float2bfloat16(v.x); xb[1] = __float2bfloat16(v.y);
  xb[2] = __float2bfloat16(v.z); xb[3] = __float2bfloat16(v.w);
}

__global__ void k_wsmall(const float* __restrict__ We, const float* __restrict__ be,
                         const float* __restrict__ Wge, const float* __restrict__ bg,
                         const float* __restrict__ Wfe, const float* __restrict__ bf,
                         float* __restrict__ weff, float* __restrict__ beff) {
  int tid = blockIdx.x * blockDim.x + threadIdx.x;
  const int WPER = RBFD * EMBD;   // 2560
  if (tid < NL * 2 * WPER) {
    int l  = tid / (2 * WPER);
    int r  = tid % (2 * WPER);
    int gf = r / WPER;
    int r2 = r % WPER;
    int k = r2 / EMBD, c = r2 % EMBD;
    const float* W = (gf == 0 ? Wge : Wfe) + (size_t)l * EMBD * EMBD;
    float s = 0.f;
    for (int j = 0; j < EMBD; ++j) s += We[k * EMBD + j] * W[(size_t)j * EMBD + c];
    weff[tid] = s;
  } else {
    int t2 = tid - NL * 2 * WPER;
    if (t2 >= NL * 2 * EMBD) return;
    int l  = t2 / (2 * EMBD);
    int r  = t2 % (2 * EMBD);
    int gf = r / EMBD, c = r % EMBD;
    const float* W = (gf == 0 ? Wge : Wfe) + (size_t)l * EMBD * EMBD;
    const float* b = (gf == 0 ? bg : bf) + (size_t)l * EMBD;
    float s = b[c];
    for (int j = 0; j < EMBD; ++j) s += be[j] * W[(size_t)j * EMBD + c];
    beff[t2] = s;
  }
}

// WT[l][q][c][k] = W_q[l][k][c] as bf16 (transposed, K-contiguous)
__global__ __launch_bounds__(256) void k_wprep(
    const float* __restrict__ Wgx, const float* __restrict__ Wfx,
    const float* __restrict__ Wgn, const float* __restrict__ Wfn,
    __hip_bfloat16* __restrict__ WT) {
  __shared__ float T[64][65];
  int lq = blockIdx.x; int l = lq >> 2, q = lq & 3;
  const float* W = (q == 0 ? Wgx : q == 1 ? Wfx : q == 2 ? Wgn : Wfn) + (size_t)l * 65536;
  int t = blockIdx.y;
  int k0 = (t & 3) * 64, c0 = (t >> 2) * 64;
  #pragma unroll
  for (int i = 0; i < 16; ++i) {
    int idx = threadIdx.x + i * 256;
    int r = idx >> 6, c = idx & 63;
    T[r][c] = W[(size_t)(k0 + r) * 256 + c0 + c];
  }
  __syncthreads();
  __hip_bfloat16* out = WT + ((size_t)lq * 256) * 256;
  #pragma unroll
  for (int i = 0; i < 16; ++i) {
    int idx = threadIdx.x + i * 256;
    int r = idx >> 6, c = idx & 63;
    out[(size_t)(c0 + r) * 256 + k0 + c] = __float2bfloat16(T[c][r]);
  }
}

// ---------------- CSR build ----------------

__global__ void k_hist(const int* __restrict__ dst, int* __restrict__ cnt) {
  int e = blockIdx.x * blockDim.x + threadIdx.x;
  if (e >= NE) return;
  atomicAdd(&cnt[dst[e]], 1);
}

__global__ __launch_bounds__(1024) void k_scan(const int* __restrict__ cnt,
                                               int* __restrict__ roff,
                                               int* __restrict__ cursor) {
  __shared__ int part[1024];
  const int t = threadIdx.x;
  const int CH = 20;
  int base = t * CH;
  int loc[CH];
  int s = 0;
  #pragma unroll
  for (int i = 0; i < CH; ++i) {
    int idx = base + i;
    int v = (idx < NN) ? cnt[idx] : 0;
    loc[i] = s;
    s += v;
  }
  part[t] = s;
  __syncthreads();
  for (int off = 1; off < 1024; off <<= 1) {
    int v = (t >= off) ? part[t - off] : 0;
    __syncthreads();
    part[t] += v;
    __syncthreads();
  }
  int chunkbase = (t == 0) ? 0 : part[t - 1];
  #pragma unroll
  for (int i = 0; i < CH; ++i) {
    int idx = base + i;
    if (idx < NN) {
      int v = chunkbase + loc[i];
      roff[idx] = v;
      cursor[idx] = v;
    }
  }
  if (t == 1023) roff[NN] = part[1023];
}

__global__ void k_scatter(const int* __restrict__ src, const int* __restrict__ dst,
                          const float* __restrict__ edist,
                          int* __restrict__ cursor,
                          int* __restrict__ src_s, float* __restrict__ rbf_s) {
  int e = blockIdx.x * blockDim.x + threadIdx.x;
  if (e >= NE) return;
  int d = dst[e];
  int p = atomicAdd(&cursor[d], 1);
  src_s[p] = src[e];
  float dd = edist[e];
  const float width = 8.0f / 9.0f;
  float r[RBFD];
  #pragma unroll
  for (int k = 0; k < RBFD; ++k) {
    float t = (dd - (float)k * width) / width;
    r[k] = __expf(-t * t);
  }
  float* rp = rbf_s + (size_t)p * RBFP;
  *(float4*)(rp + 0) = make_float4(r[0], r[1], r[2], r[3]);
  *(float4*)(rp + 4) = make_float4(r[4], r[5], r[6], r[7]);
  *(float4*)(rp + 8) = make_float4(r[8], r[9], 0.f, 0.f);
}

// ---------------- per-layer kernels ----------------

// Yb(20000 x 1024, bf16) = xnb @ [Wg_x | Wf_x | Wg_n | Wf_n]  (bf16 MFMA)
__global__ __launch_bounds__(256) void k_nodemm(
    const __hip_bfloat16* __restrict__ xnb, const __hip_bfloat16* __restrict__ WTl,
    __hip_bfloat16* __restrict__ Yb) {
  __shared__ unsigned short As[128 * 32];
  __shared__ unsigned short Bs[128 * 32];
  const int tid = threadIdx.x;
  const int lane = tid & 63;
  const int wave = tid >> 6;
  const int row0 = blockIdx.x << 7;
  const int by = blockIdx.y;
  const int col0 = by << 7;
  const int q = col0 >> 8;
  const int cb = col0 & 255;
  const unsigned short* xb = (const unsigned short*)xnb;
  const unsigned short* Wb = (const unsigned short*)WTl + ((size_t)q * 256 + cb) * 256;
  const int wr = (wave >> 1) << 6;
  const int wc = (wave & 1) << 6;
  f32x4 acc[4][4] = {};

  for (int k0 = 0; k0 < 256; k0 += 32) {
    #pragma unroll
    for (int h = 0; h < 2; ++h) {
      int c = tid + (h << 8);
      int r = c >> 2, s = c & 3;
      int sw = s ^ ((r >> 1) & 3);
      int ga = row0 + r; if (ga > NN - 1) ga = NN - 1;
      *(bf16x8*)(&As[r * 32 + sw * 8]) =
          *(const bf16x8*)(xb + (size_t)ga * 256 + k0 + s * 8);
      *(bf16x8*)(&Bs[r * 32 + sw * 8]) =
          *(const bf16x8*)(Wb + (size_t)r * 256 + k0 + s * 8);
    }
    __syncthreads();
    bf16x8 af[4], bfr[4];
    const int rsel = lane & 15, ksl = lane >> 4;
    #pragma unroll
    for (int m = 0; m < 4; ++m) {
      int r = wr + m * 16 + rsel;
      int sw = ksl ^ ((r >> 1) & 3);
      af[m] = *(const bf16x8*)(&As[r * 32 + sw * 8]);
    }
    #pragma unroll
    for (int n = 0; n < 4; ++n) {
      int r = wc + n * 16 + rsel;
      int sw = ksl ^ ((r >> 1) & 3);
      bfr[n] = *(const bf16x8*)(&Bs[r * 32 + sw * 8]);
    }
    #pragma unroll
    for (int m = 0; m < 4; ++m)
      #pragma unroll
      for (int n = 0; n < 4; ++n)
        acc[m][n] = __builtin_amdgcn_mfma_f32_16x16x32_bf16(af[m], bfr[n], acc[m][n], 0, 0, 0);
    __syncthreads();
  }

  const int crow = (lane >> 4) << 2;
  const int ccol = lane & 15;
  #pragma unroll
  for (int m = 0; m < 4; ++m)
    #pragma unroll
    for (int j = 0; j < 4; ++j) {
      int gr = row0 + wr + m * 16 + crow + j;
      if (gr < NN) {
        #pragma unroll
        for (int n = 0; n < 4; ++n)
          Yb[(size_t)gr * 1024 + col0 + wc + n * 16 + ccol] = __float2bfloat16(acc[m][n][j]);
      }
    }
}

__device__ __forceinline__ float fast_sigmoid(float z) {
  return __builtin_amdgcn_rcpf(1.0f + __expf(-z));
}
__device__ __forceinline__ float fast_softplus(float z) {
  return fmaxf(z, 0.0f) + __logf(1.0f + __expf(-fabsf(z)));
}

// one wave per dst node: W slice in REGISTERS (loaded from global, no LDS),
// coalesced src preload + shfl broadcast, vector rbf loads, 1-deep pipeline
__global__ __launch_bounds__(256, 3) void k_agg(
    const __hip_bfloat16* __restrict__ Yb, const int* __restrict__ roff,
    const int* __restrict__ src_s, const float* __restrict__ rbf_s,
    const float* __restrict__ weff, const float* __restrict__ beff,
    float* __restrict__ xn, __hip_bfloat16* __restrict__ xnb, int layer) {
  const int wave = threadIdx.x >> 6, lane = threadIdx.x & 63;
  const int c4 = lane << 2;
  const int n = blockIdx.x * 4 + wave;
  if (n >= NN) return;
  const int jb = __builtin_amdgcn_readfirstlane(roff[n]);
  const int deg = roff[n + 1] - jb;

  // per-lane W slice -> registers (L2-resident, once per node)
  const float* wg_g = weff + (size_t)layer * 2 * RBFD * EMBD + c4;
  const float* wf_g = wg_g + RBFD * EMBD;
  f32x4 wg[RBFD], wf[RBFD];
  #pragma unroll
  for (int k = 0; k < RBFD; ++k) {
    wg[k] = *(const f32x4*)(wg_g + k * EMBD);
    wf[k] = *(const f32x4*)(wf_g + k * EMBD);
  }
  const float* bb = beff + (size_t)layer * 2 * EMBD + c4;
  f32x4 bgv = *(const f32x4*)(bb);
  f32x4 bfv = *(const f32x4*)(bb + EMBD);

  // dst terms (streaming, bf16)
  const unsigned short* yrow = (const unsigned short*)Yb + (size_t)n * 1024 + c4;
  f32x4 bg = bgv + unpk(*(const uint2*)(yrow));
  f32x4 bf = bfv + unpk(*(const uint2*)(yrow + 256));

  f32x4 macc = {};
  if (deg > 0) {
    int sv = (lane < deg) ? src_s[jb + lane] : 0;   // coalesced preload
    const unsigned short* Ysrc = (const unsigned short*)Yb + c4 + 512;
    int s0 = __shfl(sv, 0, 64);
    uint2 pa = *(const uint2*)(Ysrc + (size_t)s0 * 1024);
    uint2 pf = *(const uint2*)(Ysrc + (size_t)s0 * 1024 + 256);
    const float* rp0 = rbf_s + (size_t)jb * RBFP;
    f32x4 r03 = *(const f32x4*)(rp0);
    f32x4 r47 = *(const f32x4*)(rp0 + 4);
    f32x2 r89 = *(const f32x2*)(rp0 + 8);
    for (int i = 0; i < deg; ++i) {
      uint2 na = pa, nf2 = pf;
      f32x4 n03 = r03, n47 = r47; f32x2 n89 = r89;
      if (i + 1 < deg) {
        int sn = (i + 1 < 64) ? __shfl(sv, i + 1, 64) : src_s[jb + i + 1];
        na  = *(const uint2*)(Ysrc + (size_t)sn * 1024);
        nf2 = *(const uint2*)(Ysrc + (size_t)sn * 1024 + 256);
        const float* rp = rbf_s + (size_t)(jb + i + 1) * RBFP;
        n03 = *(const f32x4*)(rp);
        n47 = *(const f32x4*)(rp + 4);
        n89 = *(const f32x2*)(rp + 8);
      }
      f32x4 zg = bg + unpk(pa);
      f32x4 zf = bf + unpk(pf);
      zg += r03.x * wg[0]; zf += r03.x * wf[0];
      zg += r03.y * wg[1]; zf += r03.y * wf[1];
      zg += r03.z * wg[2]; zf += r03.z * wf[2];
      zg += r03.w * wg[3]; zf += r03.w * wf[3];
      zg += r47.x * wg[4]; zf += r47.x * wf[4];
      zg += r47.y * wg[5]; zf += r47.y * wf[5];
      zg += r47.z * wg[6]; zf += r47.z * wf[6];
      zg += r47.w * wg[7]; zf += r47.w * wf[7];
      zg += r89.x * wg[8]; zf += r89.x * wf[8];
      zg += r89.y * wg[9]; zf += r89.y * wf[9];
      macc.x += fast_sigmoid(zg.x) * fast_softplus(zf.x);
      macc.y += fast_sigmoid(zg.y) * fast_softplus(zf.y);
      macc.z += fast_sigmoid(zg.z) * fast_softplus(zf.z);
      macc.w += fast_sigmoid(zg.w) * fast_softplus(zf.w);
      pa = na; pf = nf2; r03 = n03; r47 = n47; r89 = n89;
    }
  }
  float4 xv = *(const float4*)(xn + (size_t)n * EMBD + c4);
  xv.x += macc.x; xv.y += macc.y; xv.z += macc.z; xv.w += macc.w;
  *(float4*)(xn + (size_t)n * EMBD + c4) = xv;
  __hip_bfloat16* xbp = xnb + (size_t)n * EMBD + c4;
  xbp[0] = __float2bfloat16(xv.x); xbp[1] = __float2bfloat16(xv.y);
  xbp[2] = __float2bfloat16(xv.z); xbp[3] = __float2bfloat16(xv.w);
}

// ---------------- readout (atomic-free, split partials) ----------------

__global__ __launch_bounds__(256) void k_gsum(
    const float* __restrict__ xn, const int* __restrict__ gi,
    float* __restrict__ gpart, float* __restrict__ gcnt) {
  const int g = blockIdx.x, p = blockIdx.y;
  int lo = 0, hi = NN;
  while (lo < hi) { int m = (lo + hi) >> 1; if (gi[m] < g) lo = m + 1; else hi = m; }
  int lo2 = lo, hi2 = NN;
  while (lo2 < hi2) { int m = (lo2 + hi2) >> 1; if (gi[m] < g + 1) lo2 = m + 1; else hi2 = m; }
  const int cntv = lo2 - lo;
  const int r0 = lo + (cntv * p) / GSPL;
  const int r1 = lo + (cntv * (p + 1)) / GSPL;
  const int c = threadIdx.x;
  float acc = 0.f;
  for (int r = r0; r < r1; ++r) acc += xn[(size_t)r * EMBD + c];
  gpart[((size_t)g * GSPL + p) * EMBD + c] = acc;
  if (p == 0 && c == 0) gcnt[g] = (float)cntv;
}

__global__ __launch_bounds__(256) void k_final(
    const float* __restrict__ gpart, const float* __restrict__ gcnt,
    const float* __restrict__ Wn, const float* __restrict__ bn,
    float* __restrict__ out) {
  __shared__ float s[EMBD];
  const int g = blockIdx.x;
  const int c = threadIdx.x;
  float v = 0.f;
  #pragma unroll
  for (int p = 0; p < GSPL; ++p) v += gpart[((size_t)g * GSPL + p) * EMBD + c];
  s[c] = v;
  __syncthreads();
  if (c < 12) {
    float acc = 0.f;
    for (int k = 0; k < EMBD; ++k) acc += s[k] * Wn[k * 12 + c];
    float cv = gcnt[g];
    out[g * 12 + c] = (cv > 0.f) ? acc / cv + bn[c] : 0.f;
  }
}

// ---------------- launch ----------------

extern "C" void kernel_launch(void* const* d_in, const int* in_sizes, int n_in,
                              void* d_out, int out_size, void* d_ws, size_t ws_size,
                              hipStream_t stream) {
  const int*   x   = (const int*)d_in[0];
  const int*   src = (const int*)d_in[1];
  const int*   dst = (const int*)d_in[2];
  const float* e   = (const float*)d_in[3];
  const int*   gi  = (const int*)d_in[4];
  const float* emb = (const float*)d_in[5];
  const float* We  = (const float*)d_in[6];
  const float* be  = (const float*)d_in[7];
  const float* Wgx = (const float*)d_in[8];
  const float* Wgn = (const float*)d_in[9];
  const float* Wge = (const float*)d_in[10];
  const float* bg  = (const float*)d_in[11];
  const float* Wfx = (const float*)d_in[12];
  const float* Wfn = (const float*)d_in[13];
  const float* Wfe = (const float*)d_in[14];
  const float* bf  = (const float*)d_in[15];
  const float* Wn  = (const float*)d_in[16];
  const float* bn  = (const float*)d_in[17];
  float* out = (float*)d_out;

  char* ws = (char*)d_ws;
  size_t off = 0;
  auto alloc = [&](size_t bytes) {
    void* p = ws + off;
    off += (bytes + 255) & ~(size_t)255;
    return p;
  };
  float*           xn    = (float*)alloc((size_t)NN * EMBD * 4);
  __hip_bfloat16*  xnb   = (__hip_bfloat16*)alloc((size_t)NN * EMBD * 2);
  __hip_bfloat16*  Yb    = (__hip_bfloat16*)alloc((size_t)NN * 1024 * 2);
  float*           rbf_s = (float*)alloc((size_t)NE * RBFP * 4);
  int*             src_s = (int*)alloc((size_t)NE * 4);
  int*             cnt   = (int*)alloc((size_t)NN * 4);
  int*             roff  = (int*)alloc((size_t)(NN + 1) * 4);
  int*             curs  = (int*)alloc((size_t)NN * 4);
  float*           weff  = (float*)alloc((size_t)NL * 2 * RBFD * EMBD * 4);
  float*           beff  = (float*)alloc((size_t)NL * 2 * EMBD * 4);
  __hip_bfloat16*  WT    = (__hip_bfloat16*)alloc((size_t)NL * 4 * 256 * 256 * 2);
  float*           gpart = (float*)alloc((size_t)NG * GSPL * EMBD * 4);
  float*           gcnt  = (float*)alloc((size_t)NG * 4);
  (void)ws_size; (void)in_sizes; (void)n_in; (void)out_size;

  hipMemsetAsync(cnt, 0, (size_t)NN * 4, stream);

  k_embed<<<(NN * (EMBD / 4) + 255) / 256, 256, 0, stream>>>(x, emb, xn, xnb);
  k_wsmall<<<(NL * 2 * (RBFD + 1) * EMBD + 255) / 256, 256, 0, stream>>>(
      We, be, Wge, bg, Wfe, bf, weff, beff);
  k_wprep<<<dim3(NL * 4, 16), 256, 0, stream>>>(Wgx, Wfx, Wgn, Wfn, WT);
  k_hist<<<(NE + 255) / 256, 256, 0, stream>>>(dst, cnt);
  k_scan<<<1, 1024, 0, stream>>>(cnt, roff, curs);
  k_scatter<<<(NE + 255) / 256, 256, 0, stream>>>(src, dst, e, curs, src_s, rbf_s);

  dim3 mmgrid((NN + 127) / 128, 8);
  for (int l = 0; l < NL; ++l) {
    k_nodemm<<<mmgrid, 256, 0, stream>>>(xnb, WT + (size_t)l * 4 * 65536, Yb);
    k_agg<<<(NN + 3) / 4, 256, 0, stream>>>(Yb, roff, src_s, rbf_s, weff, beff, xn, xnb, l);
  }
  k_gsum<<<dim3(NG, GSPL), 256, 0, stream>>>(xn, gi, gpart, gcnt);
  k_final<<<NG, 256, 0, stream>>>(gpart, gcnt, Wn, bn, out);
}

// Round 8
// 517.236 us; speedup vs baseline: 1.0964x; 1.0964x over previous
//
#include <hip/hip_runtime.h>
#include <hip/hip_bf16.h>
#include <math.h>

#define NN   20000
#define NE   200000
#define NG   128
#define EMBD 256
#define NL   4
#define RBFD 10
#define RBFP 12   // padded rbf row stride (16B-aligned rows)
#define GSPL 8

typedef __attribute__((ext_vector_type(8))) short bf16x8;
typedef __attribute__((ext_vector_type(4))) float f32x4;
typedef __attribute__((ext_vector_type(2))) float f32x2;

__device__ __forceinline__ f32x2 up2(unsigned u) {
  f32x2 r;
  r.x = __uint_as_float(u << 16);
  r.y = __uint_as_float(u & 0xffff0000u);
  return r;
}

// ---------------- prep kernels ----------------

__global__ void k_embed(const int* __restrict__ x, const float* __restrict__ emb,
                        float* __restrict__ xn, __hip_bfloat16* __restrict__ xnb) {
  int idx = blockIdx.x * blockDim.x + threadIdx.x;   // float4 index
  if (idx >= NN * (EMBD / 4)) return;
  int n  = idx >> 6;
  int c4 = (idx & 63) << 2;
  float4 v = *(const float4*)(emb + (size_t)x[n] * EMBD + c4);
  *(float4*)(xn + (size_t)n * EMBD + c4) = v;
  __hip_bfloat16* xb = xnb + (size_t)n * EMBD + c4;
  xb[0] = __float2bfloat16(v.x); xb[1] = __float2bfloat16(v.y);
  xb[2] = __float2bfloat16(v.z); xb[3] = __float2bfloat16(v.w);
}

__global__ void k_wsmall(const float* __restrict__ We, const float* __restrict__ be,
                         const float* __restrict__ Wge, const float* __restrict__ bg,
                         const float* __restrict__ Wfe, const float* __restrict__ bf,
                         float* __restrict__ weff, float* __restrict__ beff) {
  int tid = blockIdx.x * blockDim.x + threadIdx.x;
  const int WPER = RBFD * EMBD;   // 2560
  if (tid < NL * 2 * WPER) {
    int l  = tid / (2 * WPER);
    int r  = tid % (2 * WPER);
    int gf = r / WPER;
    int r2 = r % WPER;
    int k = r2 / EMBD, c = r2 % EMBD;
    const float* W = (gf == 0 ? Wge : Wfe) + (size_t)l * EMBD * EMBD;
    float s = 0.f;
    for (int j = 0; j < EMBD; ++j) s += We[k * EMBD + j] * W[(size_t)j * EMBD + c];
    weff[tid] = s;
  } else {
    int t2 = tid - NL * 2 * WPER;
    if (t2 >= NL * 2 * EMBD) return;
    int l  = t2 / (2 * EMBD);
    int r  = t2 % (2 * EMBD);
    int gf = r / EMBD, c = r % EMBD;
    const float* W = (gf == 0 ? Wge : Wfe) + (size_t)l * EMBD * EMBD;
    const float* b = (gf == 0 ? bg : bf) + (size_t)l * EMBD;
    float s = b[c];
    for (int j = 0; j < EMBD; ++j) s += be[j] * W[(size_t)j * EMBD + c];
    beff[t2] = s;
  }
}

// WT[l][q][c][k] = W_q[l][k][c] as bf16 (transposed, K-contiguous)
__global__ __launch_bounds__(256) void k_wprep(
    const float* __restrict__ Wgx, const float* __restrict__ Wfx,
    const float* __restrict__ Wgn, const float* __restrict__ Wfn,
    __hip_bfloat16* __restrict__ WT) {
  __shared__ float T[64][65];
  int lq = blockIdx.x; int l = lq >> 2, q = lq & 3;
  const float* W = (q == 0 ? Wgx : q == 1 ? Wfx : q == 2 ? Wgn : Wfn) + (size_t)l * 65536;
  int t = blockIdx.y;
  int k0 = (t & 3) * 64, c0 = (t >> 2) * 64;
  #pragma unroll
  for (int i = 0; i < 16; ++i) {
    int idx = threadIdx.x + i * 256;
    int r = idx >> 6, c = idx & 63;
    T[r][c] = W[(size_t)(k0 + r) * 256 + c0 + c];
  }
  __syncthreads();
  __hip_bfloat16* out = WT + ((size_t)lq * 256) * 256;
  #pragma unroll
  for (int i = 0; i < 16; ++i) {
    int idx = threadIdx.x + i * 256;
    int r = idx >> 6, c = idx & 63;
    out[(size_t)(c0 + r) * 256 + k0 + c] = __float2bfloat16(T[c][r]);
  }
}

// ---------------- CSR build ----------------

__global__ void k_hist(const int* __restrict__ dst, int* __restrict__ cnt) {
  int e = blockIdx.x * blockDim.x + threadIdx.x;
  if (e >= NE) return;
  atomicAdd(&cnt[dst[e]], 1);
}

__global__ __launch_bounds__(1024) void k_scan(const int* __restrict__ cnt,
                                               int* __restrict__ roff,
                                               int* __restrict__ cursor) {
  __shared__ int part[1024];
  const int t = threadIdx.x;
  const int CH = 20;
  int base = t * CH;
  int loc[CH];
  int s = 0;
  #pragma unroll
  for (int i = 0; i < CH; ++i) {
    int idx = base + i;
    int v = (idx < NN) ? cnt[idx] : 0;
    loc[i] = s;
    s += v;
  }
  part[t] = s;
  __syncthreads();
  for (int off = 1; off < 1024; off <<= 1) {
    int v = (t >= off) ? part[t - off] : 0;
    __syncthreads();
    part[t] += v;
    __syncthreads();
  }
  int chunkbase = (t == 0) ? 0 : part[t - 1];
  #pragma unroll
  for (int i = 0; i < CH; ++i) {
    int idx = base + i;
    if (idx < NN) {
      int v = chunkbase + loc[i];
      roff[idx] = v;
      cursor[idx] = v;
    }
  }
  if (t == 1023) roff[NN] = part[1023];
}

__global__ void k_scatter(const int* __restrict__ src, const int* __restrict__ dst,
                          const float* __restrict__ edist,
                          int* __restrict__ cursor,
                          int* __restrict__ src_s, float* __restrict__ rbf_s) {
  int e = blockIdx.x * blockDim.x + threadIdx.x;
  if (e >= NE) return;
  int d = dst[e];
  int p = atomicAdd(&cursor[d], 1);
  src_s[p] = src[e];
  float dd = edist[e];
  const float width = 8.0f / 9.0f;
  float r[RBFD];
  #pragma unroll
  for (int k = 0; k < RBFD; ++k) {
    float t = (dd - (float)k * width) / width;
    r[k] = __expf(-t * t);
  }
  float* rp = rbf_s + (size_t)p * RBFP;
  *(float4*)(rp + 0) = make_float4(r[0], r[1], r[2], r[3]);
  *(float4*)(rp + 4) = make_float4(r[4], r[5], r[6], r[7]);
  *(float4*)(rp + 8) = make_float4(r[8], r[9], 0.f, 0.f);
}

// ---------------- per-layer kernels ----------------

// Yb(20000 x 1024, bf16) = xnb @ [Wg_x | Wf_x | Wg_n | Wf_n]  (bf16 MFMA)
__global__ __launch_bounds__(256) void k_nodemm(
    const __hip_bfloat16* __restrict__ xnb, const __hip_bfloat16* __restrict__ WTl,
    __hip_bfloat16* __restrict__ Yb) {
  __shared__ unsigned short As[128 * 32];
  __shared__ unsigned short Bs[128 * 32];
  const int tid = threadIdx.x;
  const int lane = tid & 63;
  const int wave = tid >> 6;
  const int row0 = blockIdx.x << 7;
  const int by = blockIdx.y;
  const int col0 = by << 7;
  const int q = col0 >> 8;
  const int cb = col0 & 255;
  const unsigned short* xb = (const unsigned short*)xnb;
  const unsigned short* Wb = (const unsigned short*)WTl + ((size_t)q * 256 + cb) * 256;
  const int wr = (wave >> 1) << 6;
  const int wc = (wave & 1) << 6;
  f32x4 acc[4][4] = {};

  for (int k0 = 0; k0 < 256; k0 += 32) {
    #pragma unroll
    for (int h = 0; h < 2; ++h) {
      int c = tid + (h << 8);
      int r = c >> 2, s = c & 3;
      int sw = s ^ ((r >> 1) & 3);
      int ga = row0 + r; if (ga > NN - 1) ga = NN - 1;
      *(bf16x8*)(&As[r * 32 + sw * 8]) =
          *(const bf16x8*)(xb + (size_t)ga * 256 + k0 + s * 8);
      *(bf16x8*)(&Bs[r * 32 + sw * 8]) =
          *(const bf16x8*)(Wb + (size_t)r * 256 + k0 + s * 8);
    }
    __syncthreads();
    bf16x8 af[4], bfr[4];
    const int rsel = lane & 15, ksl = lane >> 4;
    #pragma unroll
    for (int m = 0; m < 4; ++m) {
      int r = wr + m * 16 + rsel;
      int sw = ksl ^ ((r >> 1) & 3);
      af[m] = *(const bf16x8*)(&As[r * 32 + sw * 8]);
    }
    #pragma unroll
    for (int n = 0; n < 4; ++n) {
      int r = wc + n * 16 + rsel;
      int sw = ksl ^ ((r >> 1) & 3);
      bfr[n] = *(const bf16x8*)(&Bs[r * 32 + sw * 8]);
    }
    #pragma unroll
    for (int m = 0; m < 4; ++m)
      #pragma unroll
      for (int n = 0; n < 4; ++n)
        acc[m][n] = __builtin_amdgcn_mfma_f32_16x16x32_bf16(af[m], bfr[n], acc[m][n], 0, 0, 0);
    __syncthreads();
  }

  const int crow = (lane >> 4) << 2;
  const int ccol = lane & 15;
  #pragma unroll
  for (int m = 0; m < 4; ++m)
    #pragma unroll
    for (int j = 0; j < 4; ++j) {
      int gr = row0 + wr + m * 16 + crow + j;
      if (gr < NN) {
        #pragma unroll
        for (int n = 0; n < 4; ++n)
          Yb[(size_t)gr * 1024 + col0 + wc + n * 16 + ccol] = __float2bfloat16(acc[m][n][j]);
      }
    }
}

// msg contribution for one channel: sigmoid(zg) * softplus(zf)
// STABLE softplus: max(z,0) + ln(1 + e^{-|z|})  (exp arg always <= 0)
__device__ __forceinline__ float gate1(float zg, float zf) {
  float sg = __builtin_amdgcn_rcpf(1.0f + __expf(-zg));
  float sp = fmaxf(zf, 0.0f) + __logf(1.0f + __expf(-fabsf(zf)));
  return sg * sp;
}

__device__ __forceinline__ void edge_accum(
    uint2 pa, uint2 pf, f32x4 ra, f32x4 rb, f32x2 rc,
    f32x2 bg01, f32x2 bg23, f32x2 bf01, f32x2 bf23,
    const f32x2* wg01, const f32x2* wg23, const f32x2* wf01, const f32x2* wf23,
    f32x2& m01, f32x2& m23) {
  f32x2 zg01 = bg01 + up2(pa.x);
  f32x2 zg23 = bg23 + up2(pa.y);
  f32x2 zf01 = bf01 + up2(pf.x);
  f32x2 zf23 = bf23 + up2(pf.y);
  zg01 += ra.x * wg01[0]; zg23 += ra.x * wg23[0]; zf01 += ra.x * wf01[0]; zf23 += ra.x * wf23[0];
  zg01 += ra.y * wg01[1]; zg23 += ra.y * wg23[1]; zf01 += ra.y * wf01[1]; zf23 += ra.y * wf23[1];
  zg01 += ra.z * wg01[2]; zg23 += ra.z * wg23[2]; zf01 += ra.z * wf01[2]; zf23 += ra.z * wf23[2];
  zg01 += ra.w * wg01[3]; zg23 += ra.w * wg23[3]; zf01 += ra.w * wf01[3]; zf23 += ra.w * wf23[3];
  zg01 += rb.x * wg01[4]; zg23 += rb.x * wg23[4]; zf01 += rb.x * wf01[4]; zf23 += rb.x * wf23[4];
  zg01 += rb.y * wg01[5]; zg23 += rb.y * wg23[5]; zf01 += rb.y * wf01[5]; zf23 += rb.y * wf23[5];
  zg01 += rb.z * wg01[6]; zg23 += rb.z * wg23[6]; zf01 += rb.z * wf01[6]; zf23 += rb.z * wf23[6];
  zg01 += rb.w * wg01[7]; zg23 += rb.w * wg23[7]; zf01 += rb.w * wf01[7]; zf23 += rb.w * wf23[7];
  zg01 += rc.x * wg01[8]; zg23 += rc.x * wg23[8]; zf01 += rc.x * wf01[8]; zf23 += rc.x * wf23[8];
  zg01 += rc.y * wg01[9]; zg23 += rc.y * wg23[9]; zf01 += rc.y * wf01[9]; zf23 += rc.y * wf23[9];
  m01.x += gate1(zg01.x, zf01.x);
  m01.y += gate1(zg01.y, zf01.y);
  m23.x += gate1(zg23.x, zf23.x);
  m23.y += gate1(zg23.y, zf23.y);
}

// one wave per dst node: W pinned in VGPRs (asm), SGPR edge addressing,
// branch-free 1-deep pipeline
__global__ __launch_bounds__(256, 3) void k_agg(
    const __hip_bfloat16* __restrict__ Yb, const int* __restrict__ roff,
    const int* __restrict__ src_s, const float* __restrict__ rbf_s,
    const float* __restrict__ weff, const float* __restrict__ beff,
    float* __restrict__ xn, __hip_bfloat16* __restrict__ xnb, int layer) {
  const int wave = threadIdx.x >> 6, lane = threadIdx.x & 63;
  const int c4 = lane << 2;
  const int n = blockIdx.x * 4 + wave;
  if (n >= NN) return;
  const int jb   = __builtin_amdgcn_readfirstlane(roff[n]);
  const int jend = __builtin_amdgcn_readfirstlane(roff[n + 1]);
  const int deg = jend - jb;

  // hoist this lane's W slice into registers, pin so RA can't rematerialize
  const float* wg_g = weff + (size_t)layer * 2 * RBFD * EMBD + c4;
  const float* wf_g = wg_g + RBFD * EMBD;
  f32x2 wg01[RBFD], wg23[RBFD], wf01[RBFD], wf23[RBFD];
  #pragma unroll
  for (int k = 0; k < RBFD; ++k) {
    wg01[k] = *(const f32x2*)(wg_g + k * EMBD);
    wg23[k] = *(const f32x2*)(wg_g + k * EMBD + 2);
    wf01[k] = *(const f32x2*)(wf_g + k * EMBD);
    wf23[k] = *(const f32x2*)(wf_g + k * EMBD + 2);
  }
  #pragma unroll
  for (int k = 0; k < RBFD; ++k) {
    asm volatile("" : "+v"(*(double*)&wg01[k]), "+v"(*(double*)&wg23[k]),
                      "+v"(*(double*)&wf01[k]), "+v"(*(double*)&wf23[k]));
  }

  const float* bb = beff + (size_t)layer * 2 * EMBD + c4;
  f32x2 bg01 = *(const f32x2*)(bb);
  f32x2 bg23 = *(const f32x2*)(bb + 2);
  f32x2 bf01 = *(const f32x2*)(bb + EMBD);
  f32x2 bf23 = *(const f32x2*)(bb + EMBD + 2);

  // dst terms
  const unsigned short* yrow = (const unsigned short*)Yb + (size_t)n * 1024 + c4;
  uint2 da = *(const uint2*)(yrow);
  uint2 df = *(const uint2*)(yrow + 256);
  bg01 += up2(da.x); bg23 += up2(da.y);
  bf01 += up2(df.x); bf23 += up2(df.y);

  f32x2 m01 = {0.f, 0.f}, m23 = {0.f, 0.f};
  if (deg > 0) {
    const int dcap = deg < 64 ? deg : 64;
    int sv = (lane < dcap) ? src_s[jb + lane] : 0;   // coalesced preload
    // prologue: edge 0
    int scur = __builtin_amdgcn_readlane(sv, 0);     // SGPR
    const unsigned short* r0 = (const unsigned short*)Yb + (size_t)scur * 1024 + c4;
    uint2 pa = *(const uint2*)(r0 + 512);
    uint2 pf = *(const uint2*)(r0 + 768);
    const float* rp0 = rbf_s + (size_t)jb * RBFP;    // uniform -> s_load
    f32x4 ra = *(const f32x4*)(rp0);
    f32x4 rb = *(const f32x4*)(rp0 + 4);
    f32x2 rc = *(const f32x2*)(rp0 + 8);
    for (int i = 0; i < dcap; ++i) {
      int inext = (i + 1 < dcap) ? i + 1 : i;        // uniform, branch-free
      int sn = __builtin_amdgcn_readlane(sv, inext); // SGPR
      const unsigned short* rn = (const unsigned short*)Yb + (size_t)sn * 1024 + c4;
      uint2 npa = *(const uint2*)(rn + 512);
      uint2 npf = *(const uint2*)(rn + 768);
      const float* rpn = rbf_s + (size_t)(jb + inext) * RBFP;
      f32x4 nra = *(const f32x4*)(rpn);
      f32x4 nrb = *(const f32x4*)(rpn + 4);
      f32x2 nrc = *(const f32x2*)(rpn + 8);
      edge_accum(pa, pf, ra, rb, rc, bg01, bg23, bf01, bf23,
                 wg01, wg23, wf01, wf23, m01, m23);
      pa = npa; pf = npf; ra = nra; rb = nrb; rc = nrc;
    }
    // rare tail (deg > 64)
    for (int i = 64; i < deg; ++i) {
      int s = src_s[jb + i];
      const unsigned short* rr = (const unsigned short*)Yb + (size_t)s * 1024 + c4;
      uint2 qa = *(const uint2*)(rr + 512);
      uint2 qf = *(const uint2*)(rr + 768);
      const float* rp2 = rbf_s + (size_t)(jb + i) * RBFP;
      edge_accum(qa, qf, *(const f32x4*)(rp2), *(const f32x4*)(rp2 + 4),
                 *(const f32x2*)(rp2 + 8), bg01, bg23, bf01, bf23,
                 wg01, wg23, wf01, wf23, m01, m23);
    }
  }
  float4 xv = *(const float4*)(xn + (size_t)n * EMBD + c4);
  xv.x += m01.x; xv.y += m01.y; xv.z += m23.x; xv.w += m23.y;
  *(float4*)(xn + (size_t)n * EMBD + c4) = xv;
  __hip_bfloat16* xbp = xnb + (size_t)n * EMBD + c4;
  xbp[0] = __float2bfloat16(xv.x); xbp[1] = __float2bfloat16(xv.y);
  xbp[2] = __float2bfloat16(xv.z); xbp[3] = __float2bfloat16(xv.w);
}

// ---------------- readout (atomic-free, split partials) ----------------

__global__ __launch_bounds__(256) void k_gsum(
    const float* __restrict__ xn, const int* __restrict__ gi,
    float* __restrict__ gpart, float* __restrict__ gcnt) {
  const int g = blockIdx.x, p = blockIdx.y;
  int lo = 0, hi = NN;
  while (lo < hi) { int m = (lo + hi) >> 1; if (gi[m] < g) lo = m + 1; else hi = m; }
  int lo2 = lo, hi2 = NN;
  while (lo2 < hi2) { int m = (lo2 + hi2) >> 1; if (gi[m] < g + 1) lo2 = m + 1; else hi2 = m; }
  const int cntv = lo2 - lo;
  const int r0 = lo + (cntv * p) / GSPL;
  const int r1 = lo + (cntv * (p + 1)) / GSPL;
  const int c = threadIdx.x;
  float acc = 0.f;
  for (int r = r0; r < r1; ++r) acc += xn[(size_t)r * EMBD + c];
  gpart[((size_t)g * GSPL + p) * EMBD + c] = acc;
  if (p == 0 && c == 0) gcnt[g] = (float)cntv;
}

__global__ __launch_bounds__(256) void k_final(
    const float* __restrict__ gpart, const float* __restrict__ gcnt,
    const float* __restrict__ Wn, const float* __restrict__ bn,
    float* __restrict__ out) {
  __shared__ float s[EMBD];
  const int g = blockIdx.x;
  const int c = threadIdx.x;
  float v = 0.f;
  #pragma unroll
  for (int p = 0; p < GSPL; ++p) v += gpart[((size_t)g * GSPL + p) * EMBD + c];
  s[c] = v;
  __syncthreads();
  if (c < 12) {
    float acc = 0.f;
    for (int k = 0; k < EMBD; ++k) acc += s[k] * Wn[k * 12 + c];
    float cv = gcnt[g];
    out[g * 12 + c] = (cv > 0.f) ? acc / cv + bn[c] : 0.f;
  }
}

// ---------------- launch ----------------

extern "C" void kernel_launch(void* const* d_in, const int* in_sizes, int n_in,
                              void* d_out, int out_size, void* d_ws, size_t ws_size,
                              hipStream_t stream) {
  const int*   x   = (const int*)d_in[0];
  const int*   src = (const int*)d_in[1];
  const int*   dst = (const int*)d_in[2];
  const float* e   = (const float*)d_in[3];
  const int*   gi  = (const int*)d_in[4];
  const float* emb = (const float*)d_in[5];
  const float* We  = (const float*)d_in[6];
  const float* be  = (const float*)d_in[7];
  const float* Wgx = (const float*)d_in[8];
  const float* Wgn = (const float*)d_in[9];
  const float* Wge = (const float*)d_in[10];
  const float* bg  = (const float*)d_in[11];
  const float* Wfx = (const float*)d_in[12];
  const float* Wfn = (const float*)d_in[13];
  const float* Wfe = (const float*)d_in[14];
  const float* bf  = (const float*)d_in[15];
  const float* Wn  = (const float*)d_in[16];
  const float* bn  = (const float*)d_in[17];
  float* out = (float*)d_out;

  char* ws = (char*)d_ws;
  size_t off = 0;
  auto alloc = [&](size_t bytes) {
    void* p = ws + off;
    off += (bytes + 255) & ~(size_t)255;
    return p;
  };
  float*           xn    = (float*)alloc((size_t)NN * EMBD * 4);
  __hip_bfloat16*  xnb   = (__hip_bfloat16*)alloc((size_t)NN * EMBD * 2);
  __hip_bfloat16*  Yb    = (__hip_bfloat16*)alloc((size_t)NN * 1024 * 2);
  float*           rbf_s = (float*)alloc((size_t)NE * RBFP * 4);
  int*             src_s = (int*)alloc((size_t)NE * 4);
  int*             cnt   = (int*)alloc((size_t)NN * 4);
  int*             roff  = (int*)alloc((size_t)(NN + 1) * 4);
  int*             curs  = (int*)alloc((size_t)NN * 4);
  float*           weff  = (float*)alloc((size_t)NL * 2 * RBFD * EMBD * 4);
  float*           beff  = (float*)alloc((size_t)NL * 2 * EMBD * 4);
  __hip_bfloat16*  WT    = (__hip_bfloat16*)alloc((size_t)NL * 4 * 256 * 256 * 2);
  float*           gpart = (float*)alloc((size_t)NG * GSPL * EMBD * 4);
  float*           gcnt  = (float*)alloc((size_t)NG * 4);
  (void)ws_size; (void)in_sizes; (void)n_in; (void)out_size;

  hipMemsetAsync(cnt, 0, (size_t)NN * 4, stream);

  k_embed<<<(NN * (EMBD / 4) + 255) / 256, 256, 0, stream>>>(x, emb, xn, xnb);
  k_wsmall<<<(NL * 2 * (RBFD + 1) * EMBD + 255) / 256, 256, 0, stream>>>(
      We, be, Wge, bg, Wfe, bf, weff, beff);
  k_wprep<<<dim3(NL * 4, 16), 256, 0, stream>>>(Wgx, Wfx, Wgn, Wfn, WT);
  k_hist<<<(NE + 255) / 256, 256, 0, stream>>>(dst, cnt);
  k_scan<<<1, 1024, 0, stream>>>(cnt, roff, curs);
  k_scatter<<<(NE + 255) / 256, 256, 0, stream>>>(src, dst, e, curs, src_s, rbf_s);

  dim3 mmgrid((NN + 127) / 128, 8);
  for (int l = 0; l < NL; ++l) {
    k_nodemm<<<mmgrid, 256, 0, stream>>>(xnb, WT + (size_t)l * 4 * 65536, Yb);
    k_agg<<<(NN + 3) / 4, 256, 0, stream>>>(Yb, roff, src_s, rbf_s, weff, beff, xn, xnb, l);
  }
  k_gsum<<<dim3(NG, GSPL), 256, 0, stream>>>(xn, gi, gpart, gcnt);
  k_final<<<NG, 256, 0, stream>>>(gpart, gcnt, Wn, bn, out);
}

// Round 9
// 515.997 us; speedup vs baseline: 1.0991x; 1.0024x over previous
//
#include <hip/hip_runtime.h>
#include <hip/hip_bf16.h>
#include <math.h>

#define NN   20000
#define NE   200000
#define NG   128
#define EMBD 256
#define NL   4
#define RBFD 10
#define RBFP 12   // padded rbf row stride (16B-aligned rows)
#define GSPL 8

typedef __attribute__((ext_vector_type(8))) short bf16x8;
typedef __attribute__((ext_vector_type(4))) float f32x4;
typedef __attribute__((ext_vector_type(2))) float f32x2;

__device__ __forceinline__ f32x2 up2(unsigned u) {
  f32x2 r;
  r.x = __uint_as_float(u << 16);
  r.y = __uint_as_float(u & 0xffff0000u);
  return r;
}

// ---------------- prep kernels ----------------

__global__ void k_embed(const int* __restrict__ x, const float* __restrict__ emb,
                        float* __restrict__ xn, __hip_bfloat16* __restrict__ xnb) {
  int idx = blockIdx.x * blockDim.x + threadIdx.x;   // float4 index
  if (idx >= NN * (EMBD / 4)) return;
  int n  = idx >> 6;
  int c4 = (idx & 63) << 2;
  float4 v = *(const float4*)(emb + (size_t)x[n] * EMBD + c4);
  *(float4*)(xn + (size_t)n * EMBD + c4) = v;
  __hip_bfloat16* xb = xnb + (size_t)n * EMBD + c4;
  xb[0] = __float2bfloat16(v.x); xb[1] = __float2bfloat16(v.y);
  xb[2] = __float2bfloat16(v.z); xb[3] = __float2bfloat16(v.w);
}

__global__ void k_wsmall(const float* __restrict__ We, const float* __restrict__ be,
                         const float* __restrict__ Wge, const float* __restrict__ bg,
                         const float* __restrict__ Wfe, const float* __restrict__ bf,
                         float* __restrict__ weff, float* __restrict__ beff) {
  int tid = blockIdx.x * blockDim.x + threadIdx.x;
  const int WPER = RBFD * EMBD;   // 2560
  if (tid < NL * 2 * WPER) {
    int l  = tid / (2 * WPER);
    int r  = tid % (2 * WPER);
    int gf = r / WPER;
    int r2 = r % WPER;
    int k = r2 / EMBD, c = r2 % EMBD;
    const float* W = (gf == 0 ? Wge : Wfe) + (size_t)l * EMBD * EMBD;
    float s = 0.f;
    for (int j = 0; j < EMBD; ++j) s += We[k * EMBD + j] * W[(size_t)j * EMBD + c];
    weff[tid] = s;
  } else {
    int t2 = tid - NL * 2 * WPER;
    if (t2 >= NL * 2 * EMBD) return;
    int l  = t2 / (2 * EMBD);
    int r  = t2 % (2 * EMBD);
    int gf = r / EMBD, c = r % EMBD;
    const float* W = (gf == 0 ? Wge : Wfe) + (size_t)l * EMBD * EMBD;
    const float* b = (gf == 0 ? bg : bf) + (size_t)l * EMBD;
    float s = b[c];
    for (int j = 0; j < EMBD; ++j) s += be[j] * W[(size_t)j * EMBD + c];
    beff[t2] = s;
  }
}

// WT[l][q][c][k] = W_q[l][k][c] as bf16 (transposed, K-contiguous)
__global__ __launch_bounds__(256) void k_wprep(
    const float* __restrict__ Wgx, const float* __restrict__ Wfx,
    const float* __restrict__ Wgn, const float* __restrict__ Wfn,
    __hip_bfloat16* __restrict__ WT) {
  __shared__ float T[64][65];
  int lq = blockIdx.x; int l = lq >> 2, q = lq & 3;
  const float* W = (q == 0 ? Wgx : q == 1 ? Wfx : q == 2 ? Wgn : Wfn) + (size_t)l * 65536;
  int t = blockIdx.y;
  int k0 = (t & 3) * 64, c0 = (t >> 2) * 64;
  #pragma unroll
  for (int i = 0; i < 16; ++i) {
    int idx = threadIdx.x + i * 256;
    int r = idx >> 6, c = idx & 63;
    T[r][c] = W[(size_t)(k0 + r) * 256 + c0 + c];
  }
  __syncthreads();
  __hip_bfloat16* out = WT + ((size_t)lq * 256) * 256;
  #pragma unroll
  for (int i = 0; i < 16; ++i) {
    int idx = threadIdx.x + i * 256;
    int r = idx >> 6, c = idx & 63;
    out[(size_t)(c0 + r) * 256 + k0 + c] = __float2bfloat16(T[c][r]);
  }
}

// ---------------- CSR build ----------------

__global__ void k_hist(const int* __restrict__ dst, int* __restrict__ cnt) {
  int e = blockIdx.x * blockDim.x + threadIdx.x;
  if (e >= NE) return;
  atomicAdd(&cnt[dst[e]], 1);
}

__global__ __launch_bounds__(1024) void k_scan(const int* __restrict__ cnt,
                                               int* __restrict__ roff,
                                               int* __restrict__ cursor) {
  __shared__ int part[1024];
  const int t = threadIdx.x;
  const int CH = 20;
  int base = t * CH;
  int loc[CH];
  int s = 0;
  #pragma unroll
  for (int i = 0; i < CH; ++i) {
    int idx = base + i;
    int v = (idx < NN) ? cnt[idx] : 0;
    loc[i] = s;
    s += v;
  }
  part[t] = s;
  __syncthreads();
  for (int off = 1; off < 1024; off <<= 1) {
    int v = (t >= off) ? part[t - off] : 0;
    __syncthreads();
    part[t] += v;
    __syncthreads();
  }
  int chunkbase = (t == 0) ? 0 : part[t - 1];
  #pragma unroll
  for (int i = 0; i < CH; ++i) {
    int idx = base + i;
    if (idx < NN) {
      int v = chunkbase + loc[i];
      roff[idx] = v;
      cursor[idx] = v;
    }
  }
  if (t == 1023) roff[NN] = part[1023];
}

__global__ void k_scatter(const int* __restrict__ src, const int* __restrict__ dst,
                          const float* __restrict__ edist,
                          int* __restrict__ cursor,
                          int* __restrict__ src_s, float* __restrict__ rbf_s) {
  int e = blockIdx.x * blockDim.x + threadIdx.x;
  if (e >= NE) return;
  int d = dst[e];
  int p = atomicAdd(&cursor[d], 1);
  src_s[p] = src[e];
  float dd = edist[e];
  const float width = 8.0f / 9.0f;
  float r[RBFD];
  #pragma unroll
  for (int k = 0; k < RBFD; ++k) {
    float t = (dd - (float)k * width) / width;
    r[k] = __expf(-t * t);
  }
  float* rp = rbf_s + (size_t)p * RBFP;
  *(float4*)(rp + 0) = make_float4(r[0], r[1], r[2], r[3]);
  *(float4*)(rp + 4) = make_float4(r[4], r[5], r[6], r[7]);
  *(float4*)(rp + 8) = make_float4(r[8], r[9], 0.f, 0.f);
}

// ---------------- per-layer kernels ----------------

// Yb(20000 x 1024, bf16) = xnb @ [Wg_x | Wf_x | Wg_n | Wf_n]  (bf16 MFMA)
__global__ __launch_bounds__(256) void k_nodemm(
    const __hip_bfloat16* __restrict__ xnb, const __hip_bfloat16* __restrict__ WTl,
    __hip_bfloat16* __restrict__ Yb) {
  __shared__ unsigned short As[128 * 32];
  __shared__ unsigned short Bs[128 * 32];
  const int tid = threadIdx.x;
  const int lane = tid & 63;
  const int wave = tid >> 6;
  const int row0 = blockIdx.x << 7;
  const int by = blockIdx.y;
  const int col0 = by << 7;
  const int q = col0 >> 8;
  const int cb = col0 & 255;
  const unsigned short* xb = (const unsigned short*)xnb;
  const unsigned short* Wb = (const unsigned short*)WTl + ((size_t)q * 256 + cb) * 256;
  const int wr = (wave >> 1) << 6;
  const int wc = (wave & 1) << 6;
  f32x4 acc[4][4] = {};

  for (int k0 = 0; k0 < 256; k0 += 32) {
    #pragma unroll
    for (int h = 0; h < 2; ++h) {
      int c = tid + (h << 8);
      int r = c >> 2, s = c & 3;
      int sw = s ^ ((r >> 1) & 3);
      int ga = row0 + r; if (ga > NN - 1) ga = NN - 1;
      *(bf16x8*)(&As[r * 32 + sw * 8]) =
          *(const bf16x8*)(xb + (size_t)ga * 256 + k0 + s * 8);
      *(bf16x8*)(&Bs[r * 32 + sw * 8]) =
          *(const bf16x8*)(Wb + (size_t)r * 256 + k0 + s * 8);
    }
    __syncthreads();
    bf16x8 af[4], bfr[4];
    const int rsel = lane & 15, ksl = lane >> 4;
    #pragma unroll
    for (int m = 0; m < 4; ++m) {
      int r = wr + m * 16 + rsel;
      int sw = ksl ^ ((r >> 1) & 3);
      af[m] = *(const bf16x8*)(&As[r * 32 + sw * 8]);
    }
    #pragma unroll
    for (int n = 0; n < 4; ++n) {
      int r = wc + n * 16 + rsel;
      int sw = ksl ^ ((r >> 1) & 3);
      bfr[n] = *(const bf16x8*)(&Bs[r * 32 + sw * 8]);
    }
    #pragma unroll
    for (int m = 0; m < 4; ++m)
      #pragma unroll
      for (int n = 0; n < 4; ++n)
        acc[m][n] = __builtin_amdgcn_mfma_f32_16x16x32_bf16(af[m], bfr[n], acc[m][n], 0, 0, 0);
    __syncthreads();
  }

  const int crow = (lane >> 4) << 2;
  const int ccol = lane & 15;
  #pragma unroll
  for (int m = 0; m < 4; ++m)
    #pragma unroll
    for (int j = 0; j < 4; ++j) {
      int gr = row0 + wr + m * 16 + crow + j;
      if (gr < NN) {
        #pragma unroll
        for (int n = 0; n < 4; ++n)
          Yb[(size_t)gr * 1024 + col0 + wc + n * 16 + ccol] = __float2bfloat16(acc[m][n][j]);
      }
    }
}

// msg contribution for one channel: sigmoid(zg) * softplus(zf)
// STABLE softplus: max(z,0) + ln(1 + e^{-|z|})  (exp arg always <= 0)
__device__ __forceinline__ float gate1(float zg, float zf) {
  float sg = __builtin_amdgcn_rcpf(1.0f + __expf(-zg));
  float sp = fmaxf(zf, 0.0f) + __logf(1.0f + __expf(-fabsf(zf)));
  return sg * sp;
}

// W slice lives in 40 NAMED f32x2 locals (no arrays, no pointers -> no scratch)
#define LDW(i) \
  f32x2 wg01_##i = *(const f32x2*)(wg_g + (i) * EMBD);      \
  f32x2 wg23_##i = *(const f32x2*)(wg_g + (i) * EMBD + 2);  \
  f32x2 wf01_##i = *(const f32x2*)(wf_g + (i) * EMBD);      \
  f32x2 wf23_##i = *(const f32x2*)(wf_g + (i) * EMBD + 2);

#define ACC1(i, rk) \
  zg01 += (rk) * wg01_##i; zg23 += (rk) * wg23_##i; \
  zf01 += (rk) * wf01_##i; zf23 += (rk) * wf23_##i;

#define EDGE_BODY(PA, PF, RA, RB_, RC) do {      \
  f32x2 zg01 = bg01 + up2((PA).x);               \
  f32x2 zg23 = bg23 + up2((PA).y);               \
  f32x2 zf01 = bf01 + up2((PF).x);               \
  f32x2 zf23 = bf23 + up2((PF).y);               \
  ACC1(0, (RA).x) ACC1(1, (RA).y) ACC1(2, (RA).z) ACC1(3, (RA).w) \
  ACC1(4, (RB_).x) ACC1(5, (RB_).y) ACC1(6, (RB_).z) ACC1(7, (RB_).w) \
  ACC1(8, (RC).x) ACC1(9, (RC).y)                \
  m01.x += gate1(zg01.x, zf01.x);                \
  m01.y += gate1(zg01.y, zf01.y);                \
  m23.x += gate1(zg23.x, zf23.x);                \
  m23.y += gate1(zg23.y, zf23.y);                \
} while (0)

// one wave per dst node: W in named VGPR locals, SGPR edge addressing,
// branch-free 1-deep pipeline
__global__ __launch_bounds__(256, 3) void k_agg(
    const __hip_bfloat16* __restrict__ Yb, const int* __restrict__ roff,
    const int* __restrict__ src_s, const float* __restrict__ rbf_s,
    const float* __restrict__ weff, const float* __restrict__ beff,
    float* __restrict__ xn, __hip_bfloat16* __restrict__ xnb, int layer) {
  const int wave = threadIdx.x >> 6, lane = threadIdx.x & 63;
  const int c4 = lane << 2;
  const int n = blockIdx.x * 4 + wave;
  if (n >= NN) return;
  const int jb   = __builtin_amdgcn_readfirstlane(roff[n]);
  const int jend = __builtin_amdgcn_readfirstlane(roff[n + 1]);
  const int deg = jend - jb;

  const float* wg_g = weff + (size_t)layer * 2 * RBFD * EMBD + c4;
  const float* wf_g = wg_g + RBFD * EMBD;
  LDW(0) LDW(1) LDW(2) LDW(3) LDW(4) LDW(5) LDW(6) LDW(7) LDW(8) LDW(9)

  const float* bb = beff + (size_t)layer * 2 * EMBD + c4;
  f32x2 bg01 = *(const f32x2*)(bb);
  f32x2 bg23 = *(const f32x2*)(bb + 2);
  f32x2 bf01 = *(const f32x2*)(bb + EMBD);
  f32x2 bf23 = *(const f32x2*)(bb + EMBD + 2);

  // dst terms
  const unsigned short* yrow = (const unsigned short*)Yb + (size_t)n * 1024 + c4;
  uint2 da = *(const uint2*)(yrow);
  uint2 df = *(const uint2*)(yrow + 256);
  bg01 += up2(da.x); bg23 += up2(da.y);
  bf01 += up2(df.x); bf23 += up2(df.y);

  f32x2 m01 = {0.f, 0.f}, m23 = {0.f, 0.f};
  if (deg > 0) {
    const int dcap = deg < 64 ? deg : 64;
    int sv = (lane < dcap) ? src_s[jb + lane] : 0;   // coalesced preload
    // prologue: edge 0
    int scur = __builtin_amdgcn_readlane(sv, 0);     // SGPR
    const unsigned short* r0p = (const unsigned short*)Yb + (size_t)scur * 1024 + c4;
    uint2 pa = *(const uint2*)(r0p + 512);
    uint2 pf = *(const uint2*)(r0p + 768);
    const float* rp0 = rbf_s + (size_t)jb * RBFP;    // uniform -> s_load
    f32x4 ra = *(const f32x4*)(rp0);
    f32x4 rb = *(const f32x4*)(rp0 + 4);
    f32x2 rc = *(const f32x2*)(rp0 + 8);
    for (int i = 0; i < dcap; ++i) {
      int inext = (i + 1 < dcap) ? i + 1 : i;        // uniform, branch-free
      int sn = __builtin_amdgcn_readlane(sv, inext); // SGPR
      const unsigned short* rn = (const unsigned short*)Yb + (size_t)sn * 1024 + c4;
      uint2 npa = *(const uint2*)(rn + 512);
      uint2 npf = *(const uint2*)(rn + 768);
      const float* rpn = rbf_s + (size_t)(jb + inext) * RBFP;
      f32x4 nra = *(const f32x4*)(rpn);
      f32x4 nrb = *(const f32x4*)(rpn + 4);
      f32x2 nrc = *(const f32x2*)(rpn + 8);
      EDGE_BODY(pa, pf, ra, rb, rc);
      pa = npa; pf = npf; ra = nra; rb = nrb; rc = nrc;
    }
    // rare tail (deg > 64)
    for (int i = 64; i < deg; ++i) {
      int s = src_s[jb + i];
      const unsigned short* rr = (const unsigned short*)Yb + (size_t)s * 1024 + c4;
      uint2 qa = *(const uint2*)(rr + 512);
      uint2 qf = *(const uint2*)(rr + 768);
      const float* rp2 = rbf_s + (size_t)(jb + i) * RBFP;
      f32x4 ta = *(const f32x4*)(rp2);
      f32x4 tb = *(const f32x4*)(rp2 + 4);
      f32x2 tc = *(const f32x2*)(rp2 + 8);
      EDGE_BODY(qa, qf, ta, tb, tc);
    }
  }
  float4 xv = *(const float4*)(xn + (size_t)n * EMBD + c4);
  xv.x += m01.x; xv.y += m01.y; xv.z += m23.x; xv.w += m23.y;
  *(float4*)(xn + (size_t)n * EMBD + c4) = xv;
  __hip_bfloat16* xbp = xnb + (size_t)n * EMBD + c4;
  xbp[0] = __float2bfloat16(xv.x); xbp[1] = __float2bfloat16(xv.y);
  xbp[2] = __float2bfloat16(xv.z); xbp[3] = __float2bfloat16(xv.w);
}

// ---------------- readout (atomic-free, split partials) ----------------

__global__ __launch_bounds__(256) void k_gsum(
    const float* __restrict__ xn, const int* __restrict__ gi,
    float* __restrict__ gpart, float* __restrict__ gcnt) {
  const int g = blockIdx.x, p = blockIdx.y;
  int lo = 0, hi = NN;
  while (lo < hi) { int m = (lo + hi) >> 1; if (gi[m] < g) lo = m + 1; else hi = m; }
  int lo2 = lo, hi2 = NN;
  while (lo2 < hi2) { int m = (lo2 + hi2) >> 1; if (gi[m] < g + 1) lo2 = m + 1; else hi2 = m; }
  const int cntv = lo2 - lo;
  const int r0 = lo + (cntv * p) / GSPL;
  const int r1 = lo + (cntv * (p + 1)) / GSPL;
  const int c = threadIdx.x;
  float acc = 0.f;
  for (int r = r0; r < r1; ++r) acc += xn[(size_t)r * EMBD + c];
  gpart[((size_t)g * GSPL + p) * EMBD + c] = acc;
  if (p == 0 && c == 0) gcnt[g] = (float)cntv;
}

__global__ __launch_bounds__(256) void k_final(
    const float* __restrict__ gpart, const float* __restrict__ gcnt,
    const float* __restrict__ Wn, const float* __restrict__ bn,
    float* __restrict__ out) {
  __shared__ float s[EMBD];
  const int g = blockIdx.x;
  const int c = threadIdx.x;
  float v = 0.f;
  #pragma unroll
  for (int p = 0; p < GSPL; ++p) v += gpart[((size_t)g * GSPL + p) * EMBD + c];
  s[c] = v;
  __syncthreads();
  if (c < 12) {
    float acc = 0.f;
    for (int k = 0; k < EMBD; ++k) acc += s[k] * Wn[k * 12 + c];
    float cv = gcnt[g];
    out[g * 12 + c] = (cv > 0.f) ? acc / cv + bn[c] : 0.f;
  }
}

// ---------------- launch ----------------

extern "C" void kernel_launch(void* const* d_in, const int* in_sizes, int n_in,
                              void* d_out, int out_size, void* d_ws, size_t ws_size,
                              hipStream_t stream) {
  const int*   x   = (const int*)d_in[0];
  const int*   src = (const int*)d_in[1];
  const int*   dst = (const int*)d_in[2];
  const float* e   = (const float*)d_in[3];
  const int*   gi  = (const int*)d_in[4];
  const float* emb = (const float*)d_in[5];
  const float* We  = (const float*)d_in[6];
  const float* be  = (const float*)d_in[7];
  const float* Wgx = (const float*)d_in[8];
  const float* Wgn = (const float*)d_in[9];
  const float* Wge = (const float*)d_in[10];
  const float* bg  = (const float*)d_in[11];
  const float* Wfx = (const float*)d_in[12];
  const float* Wfn = (const float*)d_in[13];
  const float* Wfe = (const float*)d_in[14];
  const float* bf  = (const float*)d_in[15];
  const float* Wn  = (const float*)d_in[16];
  const float* bn  = (const float*)d_in[17];
  float* out = (float*)d_out;

  char* ws = (char*)d_ws;
  size_t off = 0;
  auto alloc = [&](size_t bytes) {
    void* p = ws + off;
    off += (bytes + 255) & ~(size_t)255;
    return p;
  };
  float*           xn    = (float*)alloc((size_t)NN * EMBD * 4);
  __hip_bfloat16*  xnb   = (__hip_bfloat16*)alloc((size_t)NN * EMBD * 2);
  __hip_bfloat16*  Yb    = (__hip_bfloat16*)alloc((size_t)NN * 1024 * 2);
  float*           rbf_s = (float*)alloc((size_t)NE * RBFP * 4);
  int*             src_s = (int*)alloc((size_t)NE * 4);
  int*             cnt   = (int*)alloc((size_t)NN * 4);
  int*             roff  = (int*)alloc((size_t)(NN + 1) * 4);
  int*             curs  = (int*)alloc((size_t)NN * 4);
  float*           weff  = (float*)alloc((size_t)NL * 2 * RBFD * EMBD * 4);
  float*           beff  = (float*)alloc((size_t)NL * 2 * EMBD * 4);
  __hip_bfloat16*  WT    = (__hip_bfloat16*)alloc((size_t)NL * 4 * 256 * 256 * 2);
  float*           gpart = (float*)alloc((size_t)NG * GSPL * EMBD * 4);
  float*           gcnt  = (float*)alloc((size_t)NG * 4);
  (void)ws_size; (void)in_sizes; (void)n_in; (void)out_size;

  hipMemsetAsync(cnt, 0, (size_t)NN * 4, stream);

  k_embed<<<(NN * (EMBD / 4) + 255) / 256, 256, 0, stream>>>(x, emb, xn, xnb);
  k_wsmall<<<(NL * 2 * (RBFD + 1) * EMBD + 255) / 256, 256, 0, stream>>>(
      We, be, Wge, bg, Wfe, bf, weff, beff);
  k_wprep<<<dim3(NL * 4, 16), 256, 0, stream>>>(Wgx, Wfx, Wgn, Wfn, WT);
  k_hist<<<(NE + 255) / 256, 256, 0, stream>>>(dst, cnt);
  k_scan<<<1, 1024, 0, stream>>>(cnt, roff, curs);
  k_scatter<<<(NE + 255) / 256, 256, 0, stream>>>(src, dst, e, curs, src_s, rbf_s);

  dim3 mmgrid((NN + 127) / 128, 8);
  for (int l = 0; l < NL; ++l) {
    k_nodemm<<<mmgrid, 256, 0, stream>>>(xnb, WT + (size_t)l * 4 * 65536, Yb);
    k_agg<<<(NN + 3) / 4, 256, 0, stream>>>(Yb, roff, src_s, rbf_s, weff, beff, xn, xnb, l);
  }
  k_gsum<<<dim3(NG, GSPL), 256, 0, stream>>>(xn, gi, gpart, gcnt);
  k_final<<<NG, 256, 0, stream>>>(gpart, gcnt, Wn, bn, out);
}

// Round 10
// 508.621 us; speedup vs baseline: 1.1150x; 1.0145x over previous
//
#include <hip/hip_runtime.h>
#include <hip/hip_bf16.h>
#include <math.h>

#define NN   20000
#define NE   200000
#define NG   128
#define EMBD 256
#define NL   4
#define RBFD 10
#define RBFP 12   // padded rbf row stride (16B-aligned rows)
#define GSPL 8

typedef __attribute__((ext_vector_type(8))) short bf16x8;
typedef __attribute__((ext_vector_type(4))) float f32x4;
typedef __attribute__((ext_vector_type(2))) float f32x2;

__device__ __forceinline__ f32x4 up4(uint2 u) {
  f32x4 r;
  r.x = __uint_as_float(u.x << 16);
  r.y = __uint_as_float(u.x & 0xffff0000u);
  r.z = __uint_as_float(u.y << 16);
  r.w = __uint_as_float(u.y & 0xffff0000u);
  return r;
}

// ---------------- prep kernels ----------------

__global__ void k_embed(const int* __restrict__ x, const float* __restrict__ emb,
                        float* __restrict__ xn, __hip_bfloat16* __restrict__ xnb) {
  int idx = blockIdx.x * blockDim.x + threadIdx.x;   // float4 index
  if (idx >= NN * (EMBD / 4)) return;
  int n  = idx >> 6;
  int c4 = (idx & 63) << 2;
  float4 v = *(const float4*)(emb + (size_t)x[n] * EMBD + c4);
  *(float4*)(xn + (size_t)n * EMBD + c4) = v;
  __hip_bfloat16* xb = xnb + (size_t)n * EMBD + c4;
  xb[0] = __float2bfloat16(v.x); xb[1] = __float2bfloat16(v.y);
  xb[2] = __float2bfloat16(v.z); xb[3] = __float2bfloat16(v.w);
}

// wpack[l][lane][k][{g0..3,f0..3}]  (320B per lane per layer, L1-resident)
// bpack[l][lane][{bg0..3,bf0..3}]
__global__ void k_wsmall(const float* __restrict__ We, const float* __restrict__ be,
                         const float* __restrict__ Wge, const float* __restrict__ bg,
                         const float* __restrict__ Wfe, const float* __restrict__ bf,
                         float* __restrict__ wpack, float* __restrict__ bpack) {
  int tid = blockIdx.x * blockDim.x + threadIdx.x;
  const int WPER = RBFD * EMBD;   // 2560
  if (tid < NL * 2 * WPER) {
    int l  = tid / (2 * WPER);
    int r  = tid % (2 * WPER);
    int gf = r / WPER;
    int r2 = r % WPER;
    int k = r2 / EMBD, c = r2 % EMBD;
    const float* W = (gf == 0 ? Wge : Wfe) + (size_t)l * EMBD * EMBD;
    float s = 0.f;
    for (int j = 0; j < EMBD; ++j) s += We[k * EMBD + j] * W[(size_t)j * EMBD + c];
    wpack[(((size_t)l * 64 + (c >> 2)) * RBFD + k) * 8 + gf * 4 + (c & 3)] = s;
  } else {
    int t2 = tid - NL * 2 * WPER;
    if (t2 >= NL * 2 * EMBD) return;
    int l  = t2 / (2 * EMBD);
    int r  = t2 % (2 * EMBD);
    int gf = r / EMBD, c = r % EMBD;
    const float* W = (gf == 0 ? Wge : Wfe) + (size_t)l * EMBD * EMBD;
    const float* b = (gf == 0 ? bg : bf) + (size_t)l * EMBD;
    float s = b[c];
    for (int j = 0; j < EMBD; ++j) s += be[j] * W[(size_t)j * EMBD + c];
    bpack[((size_t)l * 64 + (c >> 2)) * 8 + gf * 4 + (c & 3)] = s;
  }
}

// WT[l][q][c][k] = W_q[l][k][c] as bf16 (transposed, K-contiguous)
__global__ __launch_bounds__(256) void k_wprep(
    const float* __restrict__ Wgx, const float* __restrict__ Wfx,
    const float* __restrict__ Wgn, const float* __restrict__ Wfn,
    __hip_bfloat16* __restrict__ WT) {
  __shared__ float T[64][65];
  int lq = blockIdx.x; int l = lq >> 2, q = lq & 3;
  const float* W = (q == 0 ? Wgx : q == 1 ? Wfx : q == 2 ? Wgn : Wfn) + (size_t)l * 65536;
  int t = blockIdx.y;
  int k0 = (t & 3) * 64, c0 = (t >> 2) * 64;
  #pragma unroll
  for (int i = 0; i < 16; ++i) {
    int idx = threadIdx.x + i * 256;
    int r = idx >> 6, c = idx & 63;
    T[r][c] = W[(size_t)(k0 + r) * 256 + c0 + c];
  }
  __syncthreads();
  __hip_bfloat16* out = WT + ((size_t)lq * 256) * 256;
  #pragma unroll
  for (int i = 0; i < 16; ++i) {
    int idx = threadIdx.x + i * 256;
    int r = idx >> 6, c = idx & 63;
    out[(size_t)(c0 + r) * 256 + k0 + c] = __float2bfloat16(T[c][r]);
  }
}

// ---------------- CSR build ----------------

__global__ void k_hist(const int* __restrict__ dst, int* __restrict__ cnt) {
  int e = blockIdx.x * blockDim.x + threadIdx.x;
  if (e >= NE) return;
  atomicAdd(&cnt[dst[e]], 1);
}

__global__ __launch_bounds__(1024) void k_scan(const int* __restrict__ cnt,
                                               int* __restrict__ roff,
                                               int* __restrict__ cursor) {
  __shared__ int part[1024];
  const int t = threadIdx.x;
  const int CH = 20;
  int base = t * CH;
  int loc[CH];
  int s = 0;
  #pragma unroll
  for (int i = 0; i < CH; ++i) {
    int idx = base + i;
    int v = (idx < NN) ? cnt[idx] : 0;
    loc[i] = s;
    s += v;
  }
  part[t] = s;
  __syncthreads();
  for (int off = 1; off < 1024; off <<= 1) {
    int v = (t >= off) ? part[t - off] : 0;
    __syncthreads();
    part[t] += v;
    __syncthreads();
  }
  int chunkbase = (t == 0) ? 0 : part[t - 1];
  #pragma unroll
  for (int i = 0; i < CH; ++i) {
    int idx = base + i;
    if (idx < NN) {
      int v = chunkbase + loc[i];
      roff[idx] = v;
      cursor[idx] = v;
    }
  }
  if (t == 1023) roff[NN] = part[1023];
}

__global__ void k_scatter(const int* __restrict__ src, const int* __restrict__ dst,
                          const float* __restrict__ edist,
                          int* __restrict__ cursor,
                          int* __restrict__ src_s, float* __restrict__ rbf_s) {
  int e = blockIdx.x * blockDim.x + threadIdx.x;
  if (e >= NE) return;
  int d = dst[e];
  int p = atomicAdd(&cursor[d], 1);
  src_s[p] = src[e];
  float dd = edist[e];
  const float width = 8.0f / 9.0f;
  float r[RBFD];
  #pragma unroll
  for (int k = 0; k < RBFD; ++k) {
    float t = (dd - (float)k * width) / width;
    r[k] = __expf(-t * t);
  }
  float* rp = rbf_s + (size_t)p * RBFP;
  *(float4*)(rp + 0) = make_float4(r[0], r[1], r[2], r[3]);
  *(float4*)(rp + 4) = make_float4(r[4], r[5], r[6], r[7]);
  *(float4*)(rp + 8) = make_float4(r[8], r[9], 0.f, 0.f);
}

// ---------------- per-layer kernels ----------------

// Yb(20000 x 1024, bf16) = xnb @ [Wg_x | Wf_x | Wg_n | Wf_n]  (bf16 MFMA)
__global__ __launch_bounds__(256) void k_nodemm(
    const __hip_bfloat16* __restrict__ xnb, const __hip_bfloat16* __restrict__ WTl,
    __hip_bfloat16* __restrict__ Yb) {
  __shared__ unsigned short As[128 * 32];
  __shared__ unsigned short Bs[128 * 32];
  const int tid = threadIdx.x;
  const int lane = tid & 63;
  const int wave = tid >> 6;
  const int row0 = blockIdx.x << 7;
  const int by = blockIdx.y;
  const int col0 = by << 7;
  const int q = col0 >> 8;
  const int cb = col0 & 255;
  const unsigned short* xb = (const unsigned short*)xnb;
  const unsigned short* Wb = (const unsigned short*)WTl + ((size_t)q * 256 + cb) * 256;
  const int wr = (wave >> 1) << 6;
  const int wc = (wave & 1) << 6;
  f32x4 acc[4][4] = {};

  for (int k0 = 0; k0 < 256; k0 += 32) {
    #pragma unroll
    for (int h = 0; h < 2; ++h) {
      int c = tid + (h << 8);
      int r = c >> 2, s = c & 3;
      int sw = s ^ ((r >> 1) & 3);
      int ga = row0 + r; if (ga > NN - 1) ga = NN - 1;
      *(bf16x8*)(&As[r * 32 + sw * 8]) =
          *(const bf16x8*)(xb + (size_t)ga * 256 + k0 + s * 8);
      *(bf16x8*)(&Bs[r * 32 + sw * 8]) =
          *(const bf16x8*)(Wb + (size_t)r * 256 + k0 + s * 8);
    }
    __syncthreads();
    bf16x8 af[4], bfr[4];
    const int rsel = lane & 15, ksl = lane >> 4;
    #pragma unroll
    for (int m = 0; m < 4; ++m) {
      int r = wr + m * 16 + rsel;
      int sw = ksl ^ ((r >> 1) & 3);
      af[m] = *(const bf16x8*)(&As[r * 32 + sw * 8]);
    }
    #pragma unroll
    for (int n = 0; n < 4; ++n) {
      int r = wc + n * 16 + rsel;
      int sw = ksl ^ ((r >> 1) & 3);
      bfr[n] = *(const bf16x8*)(&Bs[r * 32 + sw * 8]);
    }
    #pragma unroll
    for (int m = 0; m < 4; ++m)
      #pragma unroll
      for (int n = 0; n < 4; ++n)
        acc[m][n] = __builtin_amdgcn_mfma_f32_16x16x32_bf16(af[m], bfr[n], acc[m][n], 0, 0, 0);
    __syncthreads();
  }

  const int crow = (lane >> 4) << 2;
  const int ccol = lane & 15;
  #pragma unroll
  for (int m = 0; m < 4; ++m)
    #pragma unroll
    for (int j = 0; j < 4; ++j) {
      int gr = row0 + wr + m * 16 + crow + j;
      if (gr < NN) {
        #pragma unroll
        for (int n = 0; n < 4; ++n)
          Yb[(size_t)gr * 1024 + col0 + wc + n * 16 + ccol] = __float2bfloat16(acc[m][n][j]);
      }
    }
}

// msg contribution for one channel: sigmoid(zg) * softplus(zf)
// STABLE softplus: max(z,0) + ln(1 + e^{-|z|})  (exp arg always <= 0)
__device__ __forceinline__ float gate1(float zg, float zf) {
  float sg = __builtin_amdgcn_rcpf(1.0f + __expf(-zg));
  float sp = fmaxf(zf, 0.0f) + __logf(1.0f + __expf(-fabsf(zf)));
  return sg * sp;
}

// lane's W slice: 10 x {g(f32x4), f(f32x4)} at ONE base, constant offsets
#define LDWP(i) \
  f32x4 g##i = *(const f32x4*)(wp + (i) * 8); \
  f32x4 f##i = *(const f32x4*)(wp + (i) * 8 + 4);

#define ACCP(i, rk) zg += (rk) * g##i; zf += (rk) * f##i;

#define EDGE_BODY(PA, PF, RA, RB_, RC) do {      \
  f32x4 zg = bgv + up4(PA);                      \
  f32x4 zf = bfv + up4(PF);                      \
  ACCP(0, (RA).x) ACCP(1, (RA).y) ACCP(2, (RA).z) ACCP(3, (RA).w) \
  ACCP(4, (RB_).x) ACCP(5, (RB_).y) ACCP(6, (RB_).z) ACCP(7, (RB_).w) \
  ACCP(8, (RC).x) ACCP(9, (RC).y)                \
  m4.x += gate1(zg.x, zf.x);                     \
  m4.y += gate1(zg.y, zf.y);                     \
  m4.z += gate1(zg.z, zf.z);                     \
  m4.w += gate1(zg.w, zf.w);                     \
} while (0)

// one wave per dst node: packed L1-resident W, SGPR edge addressing,
// 2-wide software pipeline
__global__ __launch_bounds__(256, 3) void k_agg(
    const __hip_bfloat16* __restrict__ Yb, const int* __restrict__ roff,
    const int* __restrict__ src_s, const float* __restrict__ rbf_s,
    const float* __restrict__ wpack, const float* __restrict__ bpack,
    float* __restrict__ xn, __hip_bfloat16* __restrict__ xnb, int layer) {
  const int wave = threadIdx.x >> 6, lane = threadIdx.x & 63;
  const int c4 = lane << 2;
  const int n = blockIdx.x * 4 + wave;
  if (n >= NN) return;
  const int jb   = __builtin_amdgcn_readfirstlane(roff[n]);
  const int jend = __builtin_amdgcn_readfirstlane(roff[n + 1]);
  const int deg = jend - jb;

  const float* wp = wpack + ((size_t)layer * 64 + lane) * (RBFD * 8);
  LDWP(0) LDWP(1) LDWP(2) LDWP(3) LDWP(4) LDWP(5) LDWP(6) LDWP(7) LDWP(8) LDWP(9)

  const float* bp = bpack + ((size_t)layer * 64 + lane) * 8;
  f32x4 bgv = *(const f32x4*)(bp);
  f32x4 bfv = *(const f32x4*)(bp + 4);

  // dst terms
  const unsigned short* yrow = (const unsigned short*)Yb + (size_t)n * 1024 + c4;
  uint2 da = *(const uint2*)(yrow);
  uint2 df = *(const uint2*)(yrow + 256);
  bgv += up4(da);
  bfv += up4(df);

  f32x4 m4 = {};
  if (deg > 0) {
    const int dcap = deg < 64 ? deg : 64;
    int sv = (lane < dcap) ? src_s[jb + lane] : 0;   // coalesced preload
    const unsigned short* Ysrc = (const unsigned short*)Yb + c4 + 512;
    // prologue: slots A=edge0, B=edge1 (clamped)
    int i1 = (dcap > 1) ? 1 : 0;
    int s0 = __builtin_amdgcn_readlane(sv, 0);
    int s1 = __builtin_amdgcn_readlane(sv, i1);
    uint2 paA = *(const uint2*)(Ysrc + (size_t)s0 * 1024);
    uint2 pfA = *(const uint2*)(Ysrc + (size_t)s0 * 1024 + 256);
    uint2 paB = *(const uint2*)(Ysrc + (size_t)s1 * 1024);
    uint2 pfB = *(const uint2*)(Ysrc + (size_t)s1 * 1024 + 256);
    const float* rpA = rbf_s + (size_t)jb * RBFP;
    const float* rpB = rbf_s + (size_t)(jb + i1) * RBFP;
    f32x4 raA = *(const f32x4*)(rpA), rbA = *(const f32x4*)(rpA + 4);
    f32x2 rcA = *(const f32x2*)(rpA + 8);
    f32x4 raB = *(const f32x4*)(rpB), rbB = *(const f32x4*)(rpB + 4);
    f32x2 rcB = *(const f32x2*)(rpB + 8);
    for (int i = 0; i < dcap; i += 2) {
      int i2 = (i + 2 < dcap) ? i + 2 : dcap - 1;    // uniform
      int i3 = (i + 3 < dcap) ? i + 3 : dcap - 1;
      int s2 = __builtin_amdgcn_readlane(sv, i2);
      int s3 = __builtin_amdgcn_readlane(sv, i3);
      uint2 npaA = *(const uint2*)(Ysrc + (size_t)s2 * 1024);
      uint2 npfA = *(const uint2*)(Ysrc + (size_t)s2 * 1024 + 256);
      uint2 npaB = *(const uint2*)(Ysrc + (size_t)s3 * 1024);
      uint2 npfB = *(const uint2*)(Ysrc + (size_t)s3 * 1024 + 256);
      const float* rp2 = rbf_s + (size_t)(jb + i2) * RBFP;
      const float* rp3 = rbf_s + (size_t)(jb + i3) * RBFP;
      f32x4 nraA = *(const f32x4*)(rp2), nrbA = *(const f32x4*)(rp2 + 4);
      f32x2 nrcA = *(const f32x2*)(rp2 + 8);
      f32x4 nraB = *(const f32x4*)(rp3), nrbB = *(const f32x4*)(rp3 + 4);
      f32x2 nrcB = *(const f32x2*)(rp3 + 8);
      EDGE_BODY(paA, pfA, raA, rbA, rcA);
      if (i + 1 < dcap) EDGE_BODY(paB, pfB, raB, rbB, rcB);
      paA = npaA; pfA = npfA; raA = nraA; rbA = nrbA; rcA = nrcA;
      paB = npaB; pfB = npfB; raB = nraB; rbB = nrbB; rcB = nrcB;
    }
    // rare tail (deg > 64)
    for (int i = 64; i < deg; ++i) {
      int s = src_s[jb + i];
      uint2 qa = *(const uint2*)(Ysrc + (size_t)s * 1024);
      uint2 qf = *(const uint2*)(Ysrc + (size_t)s * 1024 + 256);
      const float* rpt = rbf_s + (size_t)(jb + i) * RBFP;
      f32x4 ta = *(const f32x4*)(rpt), tb = *(const f32x4*)(rpt + 4);
      f32x2 tc = *(const f32x2*)(rpt + 8);
      EDGE_BODY(qa, qf, ta, tb, tc);
    }
  }
  float4 xv = *(const float4*)(xn + (size_t)n * EMBD + c4);
  xv.x += m4.x; xv.y += m4.y; xv.z += m4.z; xv.w += m4.w;
  *(float4*)(xn + (size_t)n * EMBD + c4) = xv;
  __hip_bfloat16* xbp = xnb + (size_t)n * EMBD + c4;
  xbp[0] = __float2bfloat16(xv.x); xbp[1] = __float2bfloat16(xv.y);
  xbp[2] = __float2bfloat16(xv.z); xbp[3] = __float2bfloat16(xv.w);
}

// ---------------- readout (atomic-free, split partials) ----------------

__global__ __launch_bounds__(256) void k_gsum(
    const float* __restrict__ xn, const int* __restrict__ gi,
    float* __restrict__ gpart, float* __restrict__ gcnt) {
  const int g = blockIdx.x, p = blockIdx.y;
  int lo = 0, hi = NN;
  while (lo < hi) { int m = (lo + hi) >> 1; if (gi[m] < g) lo = m + 1; else hi = m; }
  int lo2 = lo, hi2 = NN;
  while (lo2 < hi2) { int m = (lo2 + hi2) >> 1; if (gi[m] < g + 1) lo2 = m + 1; else hi2 = m; }
  const int cntv = lo2 - lo;
  const int r0 = lo + (cntv * p) / GSPL;
  const int r1 = lo + (cntv * (p + 1)) / GSPL;
  const int c = threadIdx.x;
  float acc = 0.f;
  for (int r = r0; r < r1; ++r) acc += xn[(size_t)r * EMBD + c];
  gpart[((size_t)g * GSPL + p) * EMBD + c] = acc;
  if (p == 0 && c == 0) gcnt[g] = (float)cntv;
}

__global__ __launch_bounds__(256) void k_final(
    const float* __restrict__ gpart, const float* __restrict__ gcnt,
    const float* __restrict__ Wn, const float* __restrict__ bn,
    float* __restrict__ out) {
  __shared__ float s[EMBD];
  const int g = blockIdx.x;
  const int c = threadIdx.x;
  float v = 0.f;
  #pragma unroll
  for (int p = 0; p < GSPL; ++p) v += gpart[((size_t)g * GSPL + p) * EMBD + c];
  s[c] = v;
  __syncthreads();
  if (c < 12) {
    float acc = 0.f;
    for (int k = 0; k < EMBD; ++k) acc += s[k] * Wn[k * 12 + c];
    float cv = gcnt[g];
    out[g * 12 + c] = (cv > 0.f) ? acc / cv + bn[c] : 0.f;
  }
}

// ---------------- launch ----------------

extern "C" void kernel_launch(void* const* d_in, const int* in_sizes, int n_in,
                              void* d_out, int out_size, void* d_ws, size_t ws_size,
                              hipStream_t stream) {
  const int*   x   = (const int*)d_in[0];
  const int*   src = (const int*)d_in[1];
  const int*   dst = (const int*)d_in[2];
  const float* e   = (const float*)d_in[3];
  const int*   gi  = (const int*)d_in[4];
  const float* emb = (const float*)d_in[5];
  const float* We  = (const float*)d_in[6];
  const float* be  = (const float*)d_in[7];
  const float* Wgx = (const float*)d_in[8];
  const float* Wgn = (const float*)d_in[9];
  const float* Wge = (const float*)d_in[10];
  const float* bg  = (const float*)d_in[11];
  const float* Wfx = (const float*)d_in[12];
  const float* Wfn = (const float*)d_in[13];
  const float* Wfe = (const float*)d_in[14];
  const float* bf  = (const float*)d_in[15];
  const float* Wn  = (const float*)d_in[16];
  const float* bn  = (const float*)d_in[17];
  float* out = (float*)d_out;

  char* ws = (char*)d_ws;
  size_t off = 0;
  auto alloc = [&](size_t bytes) {
    void* p = ws + off;
    off += (bytes + 255) & ~(size_t)255;
    return p;
  };
  float*           xn    = (float*)alloc((size_t)NN * EMBD * 4);
  __hip_bfloat16*  xnb   = (__hip_bfloat16*)alloc((size_t)NN * EMBD * 2);
  __hip_bfloat16*  Yb    = (__hip_bfloat16*)alloc((size_t)NN * 1024 * 2);
  float*           rbf_s = (float*)alloc((size_t)NE * RBFP * 4);
  int*             src_s = (int*)alloc((size_t)NE * 4);
  int*             cnt   = (int*)alloc((size_t)NN * 4);
  int*             roff  = (int*)alloc((size_t)(NN + 1) * 4);
  int*             curs  = (int*)alloc((size_t)NN * 4);
  float*           wpack = (float*)alloc((size_t)NL * 64 * RBFD * 8 * 4);
  float*           bpack = (float*)alloc((size_t)NL * 64 * 8 * 4);
  __hip_bfloat16*  WT    = (__hip_bfloat16*)alloc((size_t)NL * 4 * 256 * 256 * 2);
  float*           gpart = (float*)alloc((size_t)NG * GSPL * EMBD * 4);
  float*           gcnt  = (float*)alloc((size_t)NG * 4);
  (void)ws_size; (void)in_sizes; (void)n_in; (void)out_size;

  hipMemsetAsync(cnt, 0, (size_t)NN * 4, stream);

  k_embed<<<(NN * (EMBD / 4) + 255) / 256, 256, 0, stream>>>(x, emb, xn, xnb);
  k_wsmall<<<(NL * 2 * (RBFD + 1) * EMBD + 255) / 256, 256, 0, stream>>>(
      We, be, Wge, bg, Wfe, bf, wpack, bpack);
  k_wprep<<<dim3(NL * 4, 16), 256, 0, stream>>>(Wgx, Wfx, Wgn, Wfn, WT);
  k_hist<<<(NE + 255) / 256, 256, 0, stream>>>(dst, cnt);
  k_scan<<<1, 1024, 0, stream>>>(cnt, roff, curs);
  k_scatter<<<(NE + 255) / 256, 256, 0, stream>>>(src, dst, e, curs, src_s, rbf_s);

  dim3 mmgrid((NN + 127) / 128, 8);
  for (int l = 0; l < NL; ++l) {
    k_nodemm<<<mmgrid, 256, 0, stream>>>(xnb, WT + (size_t)l * 4 * 65536, Yb);
    k_agg<<<(NN + 3) / 4, 256, 0, stream>>>(Yb, roff, src_s, rbf_s, wpack, bpack, xn, xnb, l);
  }
  k_gsum<<<dim3(NG, GSPL), 256, 0, stream>>>(xn, gi, gpart, gcnt);
  k_final<<<NG, 256, 0, stream>>>(gpart, gcnt, Wn, bn, out);
}

// Round 11
// 490.386 us; speedup vs baseline: 1.1565x; 1.0372x over previous
//
#include <hip/hip_runtime.h>
#include <hip/hip_bf16.h>
#include <math.h>

#define NN   20000
#define NE   200000
#define NG   128
#define EMBD 256
#define NL   4
#define RBFD 10
#define TBINS 1024      // lerp bins over d in [0,8]; table rows = TBINS+1
#define NWAVE 8192      // persistent waves in k_agg (2048 blocks x 4)
#define GSPL 8

typedef __attribute__((ext_vector_type(8))) short bf16x8;
typedef __attribute__((ext_vector_type(4))) float f32x4;

__device__ __forceinline__ f32x4 up4(uint2 u) {
  f32x4 r;
  r.x = __uint_as_float(u.x << 16);
  r.y = __uint_as_float(u.x & 0xffff0000u);
  r.z = __uint_as_float(u.y << 16);
  r.w = __uint_as_float(u.y & 0xffff0000u);
  return r;
}

// ---------------- prep kernels ----------------

__global__ void k_embed(const int* __restrict__ x, const float* __restrict__ emb,
                        float* __restrict__ xn, __hip_bfloat16* __restrict__ xnb) {
  int idx = blockIdx.x * blockDim.x + threadIdx.x;   // float4 index
  if (idx >= NN * (EMBD / 4)) return;
  int n  = idx >> 6;
  int c4 = (idx & 63) << 2;
  float4 v = *(const float4*)(emb + (size_t)x[n] * EMBD + c4);
  *(float4*)(xn + (size_t)n * EMBD + c4) = v;
  __hip_bfloat16* xb = xnb + (size_t)n * EMBD + c4;
  xb[0] = __float2bfloat16(v.x); xb[1] = __float2bfloat16(v.y);
  xb[2] = __float2bfloat16(v.z); xb[3] = __float2bfloat16(v.w);
}

// weff[l][gf][k][c] = (We @ W*_e[l])[k][c];  beff[l][gf][c] = be @ W*_e[l] + b*[l]
__global__ void k_wsmall(const float* __restrict__ We, const float* __restrict__ be,
                         const float* __restrict__ Wge, const float* __restrict__ bg,
                         const float* __restrict__ Wfe, const float* __restrict__ bf,
                         float* __restrict__ weff, float* __restrict__ beff) {
  int tid = blockIdx.x * blockDim.x + threadIdx.x;
  const int WPER = RBFD * EMBD;   // 2560
  if (tid < NL * 2 * WPER) {
    int l  = tid / (2 * WPER);
    int r  = tid % (2 * WPER);
    int gf = r / WPER;
    int r2 = r % WPER;
    int k = r2 / EMBD, c = r2 % EMBD;
    const float* W = (gf == 0 ? Wge : Wfe) + (size_t)l * EMBD * EMBD;
    float s = 0.f;
    for (int j = 0; j < EMBD; ++j) s += We[k * EMBD + j] * W[(size_t)j * EMBD + c];
    weff[tid] = s;
  } else {
    int t2 = tid - NL * 2 * WPER;
    if (t2 >= NL * 2 * EMBD) return;
    int l  = t2 / (2 * EMBD);
    int r  = t2 % (2 * EMBD);
    int gf = r / EMBD, c = r % EMBD;
    const float* W = (gf == 0 ? Wge : Wfe) + (size_t)l * EMBD * EMBD;
    const float* b = (gf == 0 ? bg : bf) + (size_t)l * EMBD;
    float s = b[c];
    for (int j = 0; j < EMBD; ++j) s += be[j] * W[(size_t)j * EMBD + c];
    beff[t2] = s;
  }
}

// tbl[l][bin][t]: t<256 -> zg contribution of distance, t>=256 -> zf; bias folded in
__global__ void k_table(const float* __restrict__ weff, const float* __restrict__ beff,
                        float* __restrict__ tbl) {
  int idx = blockIdx.x * blockDim.x + threadIdx.x;
  if (idx >= NL * (TBINS + 1) * 512) return;
  int l = idx / ((TBINS + 1) * 512);
  int r = idx % ((TBINS + 1) * 512);
  int bin = r >> 9;
  int t = r & 511;
  int gf = t >> 8, c = t & 255;
  float d = (float)bin * (8.0f / (float)TBINS);
  const float* w = weff + ((size_t)(l * 2 + gf) * RBFD) * EMBD + c;
  float s = beff[(size_t)(l * 2 + gf) * EMBD + c];
  const float width = 8.0f / 9.0f;
  #pragma unroll
  for (int k = 0; k < RBFD; ++k) {
    float u = (d - (float)k * width) / width;
    s += __expf(-u * u) * w[(size_t)k * EMBD];
  }
  tbl[idx] = s;
}

// WT[l][q][c][k] = W_q[l][k][c] as bf16 (transposed, K-contiguous)
__global__ __launch_bounds__(256) void k_wprep(
    const float* __restrict__ Wgx, const float* __restrict__ Wfx,
    const float* __restrict__ Wgn, const float* __restrict__ Wfn,
    __hip_bfloat16* __restrict__ WT) {
  __shared__ float T[64][65];
  int lq = blockIdx.x; int l = lq >> 2, q = lq & 3;
  const float* W = (q == 0 ? Wgx : q == 1 ? Wfx : q == 2 ? Wgn : Wfn) + (size_t)l * 65536;
  int t = blockIdx.y;
  int k0 = (t & 3) * 64, c0 = (t >> 2) * 64;
  #pragma unroll
  for (int i = 0; i < 16; ++i) {
    int idx = threadIdx.x + i * 256;
    int r = idx >> 6, c = idx & 63;
    T[r][c] = W[(size_t)(k0 + r) * 256 + c0 + c];
  }
  __syncthreads();
  __hip_bfloat16* out = WT + ((size_t)lq * 256) * 256;
  #pragma unroll
  for (int i = 0; i < 16; ++i) {
    int idx = threadIdx.x + i * 256;
    int r = idx >> 6, c = idx & 63;
    out[(size_t)(c0 + r) * 256 + k0 + c] = __float2bfloat16(T[c][r]);
  }
}

// ---------------- CSR build ----------------

__global__ void k_hist(const int* __restrict__ dst, int* __restrict__ cnt) {
  int e = blockIdx.x * blockDim.x + threadIdx.x;
  if (e >= NE) return;
  atomicAdd(&cnt[dst[e]], 1);
}

__global__ __launch_bounds__(1024) void k_scan(const int* __restrict__ cnt,
                                               int* __restrict__ roff,
                                               int* __restrict__ cursor) {
  __shared__ int part[1024];
  const int t = threadIdx.x;
  const int CH = 20;
  int base = t * CH;
  int loc[CH];
  int s = 0;
  #pragma unroll
  for (int i = 0; i < CH; ++i) {
    int idx = base + i;
    int v = (idx < NN) ? cnt[idx] : 0;
    loc[i] = s;
    s += v;
  }
  part[t] = s;
  __syncthreads();
  for (int off = 1; off < 1024; off <<= 1) {
    int v = (t >= off) ? part[t - off] : 0;
    __syncthreads();
    part[t] += v;
    __syncthreads();
  }
  int chunkbase = (t == 0) ? 0 : part[t - 1];
  #pragma unroll
  for (int i = 0; i < CH; ++i) {
    int idx = base + i;
    if (idx < NN) {
      int v = chunkbase + loc[i];
      roff[idx] = v;
      cursor[idx] = v;
    }
  }
  if (t == 1023) roff[NN] = part[1023];
}

// scatter edges dst-sorted; store src and scaled distance (bin space)
__global__ void k_scatter(const int* __restrict__ src, const int* __restrict__ dst,
                          const float* __restrict__ edist,
                          int* __restrict__ cursor,
                          int* __restrict__ src_s, float* __restrict__ db_s) {
  int e = blockIdx.x * blockDim.x + threadIdx.x;
  if (e >= NE) return;
  int d = dst[e];
  int p = atomicAdd(&cursor[d], 1);
  src_s[p] = src[e];
  float dd = edist[e] * ((float)TBINS / 8.0f);
  db_s[p] = fminf(fmaxf(dd, 0.0f), (float)TBINS - 0.001f);
}

// ---------------- per-layer kernels ----------------

// Yb(20000 x 1024, bf16) = xnb @ [Wg_x | Wf_x | Wg_n | Wf_n]  (bf16 MFMA)
__global__ __launch_bounds__(256) void k_nodemm(
    const __hip_bfloat16* __restrict__ xnb, const __hip_bfloat16* __restrict__ WTl,
    __hip_bfloat16* __restrict__ Yb) {
  __shared__ unsigned short As[128 * 32];
  __shared__ unsigned short Bs[128 * 32];
  const int tid = threadIdx.x;
  const int lane = tid & 63;
  const int wave = tid >> 6;
  const int row0 = blockIdx.x << 7;
  const int by = blockIdx.y;
  const int col0 = by << 7;
  const int q = col0 >> 8;
  const int cb = col0 & 255;
  const unsigned short* xb = (const unsigned short*)xnb;
  const unsigned short* Wb = (const unsigned short*)WTl + ((size_t)q * 256 + cb) * 256;
  const int wr = (wave >> 1) << 6;
  const int wc = (wave & 1) << 6;
  f32x4 acc[4][4] = {};

  for (int k0 = 0; k0 < 256; k0 += 32) {
    #pragma unroll
    for (int h = 0; h < 2; ++h) {
      int c = tid + (h << 8);
      int r = c >> 2, s = c & 3;
      int sw = s ^ ((r >> 1) & 3);
      int ga = row0 + r; if (ga > NN - 1) ga = NN - 1;
      *(bf16x8*)(&As[r * 32 + sw * 8]) =
          *(const bf16x8*)(xb + (size_t)ga * 256 + k0 + s * 8);
      *(bf16x8*)(&Bs[r * 32 + sw * 8]) =
          *(const bf16x8*)(Wb + (size_t)r * 256 + k0 + s * 8);
    }
    __syncthreads();
    bf16x8 af[4], bfr[4];
    const int rsel = lane & 15, ksl = lane >> 4;
    #pragma unroll
    for (int m = 0; m < 4; ++m) {
      int r = wr + m * 16 + rsel;
      int sw = ksl ^ ((r >> 1) & 3);
      af[m] = *(const bf16x8*)(&As[r * 32 + sw * 8]);
    }
    #pragma unroll
    for (int n = 0; n < 4; ++n) {
      int r = wc + n * 16 + rsel;
      int sw = ksl ^ ((r >> 1) & 3);
      bfr[n] = *(const bf16x8*)(&Bs[r * 32 + sw * 8]);
    }
    #pragma unroll
    for (int m = 0; m < 4; ++m)
      #pragma unroll
      for (int n = 0; n < 4; ++n)
        acc[m][n] = __builtin_amdgcn_mfma_f32_16x16x32_bf16(af[m], bfr[n], acc[m][n], 0, 0, 0);
    __syncthreads();
  }

  const int crow = (lane >> 4) << 2;
  const int ccol = lane & 15;
  #pragma unroll
  for (int m = 0; m < 4; ++m)
    #pragma unroll
    for (int j = 0; j < 4; ++j) {
      int gr = row0 + wr + m * 16 + crow + j;
      if (gr < NN) {
        #pragma unroll
        for (int n = 0; n < 4; ++n)
          Yb[(size_t)gr * 1024 + col0 + wc + n * 16 + ccol] = __float2bfloat16(acc[m][n][j]);
      }
    }
}

// msg contribution for one channel: sigmoid(zg) * softplus(zf)
// STABLE softplus: max(z,0) + ln(1 + e^{-|z|})
__device__ __forceinline__ float gate1(float zg, float zf) {
  float sg = __builtin_amdgcn_rcpf(1.0f + __expf(-zg));
  float sp = fmaxf(zf, 0.0f) + __logf(1.0f + __expf(-fabsf(zf)));
  return sg * sp;
}

// persistent grid-stride waves; per edge: 2 bf16 gathers + 4 table loads + lerp
__global__ __launch_bounds__(256, 8) void k_agg(
    const __hip_bfloat16* __restrict__ Yb, const int* __restrict__ roff,
    const int* __restrict__ src_s, const float* __restrict__ db_s,
    const float* __restrict__ tblL,
    float* __restrict__ xn, __hip_bfloat16* __restrict__ xnb) {
  const int wave = threadIdx.x >> 6, lane = threadIdx.x & 63;
  const int c4 = lane << 2;
  const int wid0 = blockIdx.x * 4 + wave;

  for (int n = wid0; n < NN; n += NWAVE) {
    const int jb   = __builtin_amdgcn_readfirstlane(roff[n]);
    const int jend = __builtin_amdgcn_readfirstlane(roff[n + 1]);
    const int deg = jend - jb;

    // dst terms (bias is folded into the table)
    const unsigned short* yrow = (const unsigned short*)Yb + (size_t)n * 1024 + c4;
    f32x4 bgv = up4(*(const uint2*)(yrow));
    f32x4 bfv = up4(*(const uint2*)(yrow + 256));

    f32x4 m4 = {};
    if (deg > 0) {
      const int dcap = deg < 64 ? deg : 64;
      int sv = 0; int bv = 0; int fv = 0;
      if (lane < dcap) {
        sv = src_s[jb + lane];
        float db = db_s[jb + lane];
        int b = (int)db;
        bv = b;
        fv = __float_as_int(db - (float)b);
      }
      const unsigned short* Ysrc = (const unsigned short*)Yb + c4 + 512;
      for (int i = 0; i < dcap; ++i) {
        int sn = __builtin_amdgcn_readlane(sv, i);
        int bn = __builtin_amdgcn_readlane(bv, i);
        float fr = __int_as_float(__builtin_amdgcn_readlane(fv, i));
        const unsigned short* ys = Ysrc + (size_t)sn * 1024;
        uint2 pa = *(const uint2*)(ys);
        uint2 pf = *(const uint2*)(ys + 256);
        const float* tp = tblL + (size_t)bn * 512 + c4;
        f32x4 t0g = *(const f32x4*)(tp);
        f32x4 t0f = *(const f32x4*)(tp + 256);
        f32x4 t1g = *(const f32x4*)(tp + 512);
        f32x4 t1f = *(const f32x4*)(tp + 768);
        f32x4 zg = bgv + up4(pa) + t0g + fr * (t1g - t0g);
        f32x4 zf = bfv + up4(pf) + t0f + fr * (t1f - t0f);
        m4.x += gate1(zg.x, zf.x);
        m4.y += gate1(zg.y, zf.y);
        m4.z += gate1(zg.z, zf.z);
        m4.w += gate1(zg.w, zf.w);
      }
      // rare tail (deg > 64): uniform scalar loads
      for (int i = 64; i < deg; ++i) {
        int sn = src_s[jb + i];
        float db = db_s[jb + i];
        int bn = (int)db;
        float fr = db - (float)bn;
        const unsigned short* ys = Ysrc + (size_t)sn * 1024;
        uint2 pa = *(const uint2*)(ys);
        uint2 pf = *(const uint2*)(ys + 256);
        const float* tp = tblL + (size_t)bn * 512 + c4;
        f32x4 t0g = *(const f32x4*)(tp);
        f32x4 t0f = *(const f32x4*)(tp + 256);
        f32x4 t1g = *(const f32x4*)(tp + 512);
        f32x4 t1f = *(const f32x4*)(tp + 768);
        f32x4 zg = bgv + up4(pa) + t0g + fr * (t1g - t0g);
        f32x4 zf = bfv + up4(pf) + t0f + fr * (t1f - t0f);
        m4.x += gate1(zg.x, zf.x);
        m4.y += gate1(zg.y, zf.y);
        m4.z += gate1(zg.z, zf.z);
        m4.w += gate1(zg.w, zf.w);
      }
    }
    float4 xv = *(const float4*)(xn + (size_t)n * EMBD + c4);
    xv.x += m4.x; xv.y += m4.y; xv.z += m4.z; xv.w += m4.w;
    *(float4*)(xn + (size_t)n * EMBD + c4) = xv;
    __hip_bfloat16* xbp = xnb + (size_t)n * EMBD + c4;
    xbp[0] = __float2bfloat16(xv.x); xbp[1] = __float2bfloat16(xv.y);
    xbp[2] = __float2bfloat16(xv.z); xbp[3] = __float2bfloat16(xv.w);
  }
}

// ---------------- readout (atomic-free, split partials) ----------------

__global__ __launch_bounds__(256) void k_gsum(
    const float* __restrict__ xn, const int* __restrict__ gi,
    float* __restrict__ gpart, float* __restrict__ gcnt) {
  const int g = blockIdx.x, p = blockIdx.y;
  int lo = 0, hi = NN;
  while (lo < hi) { int m = (lo + hi) >> 1; if (gi[m] < g) lo = m + 1; else hi = m; }
  int lo2 = lo, hi2 = NN;
  while (lo2 < hi2) { int m = (lo2 + hi2) >> 1; if (gi[m] < g + 1) lo2 = m + 1; else hi2 = m; }
  const int cntv = lo2 - lo;
  const int r0 = lo + (cntv * p) / GSPL;
  const int r1 = lo + (cntv * (p + 1)) / GSPL;
  const int c = threadIdx.x;
  float acc = 0.f;
  for (int r = r0; r < r1; ++r) acc += xn[(size_t)r * EMBD + c];
  gpart[((size_t)g * GSPL + p) * EMBD + c] = acc;
  if (p == 0 && c == 0) gcnt[g] = (float)cntv;
}

__global__ __launch_bounds__(256) void k_final(
    const float* __restrict__ gpart, const float* __restrict__ gcnt,
    const float* __restrict__ Wn, const float* __restrict__ bn,
    float* __restrict__ out) {
  __shared__ float s[EMBD];
  const int g = blockIdx.x;
  const int c = threadIdx.x;
  float v = 0.f;
  #pragma unroll
  for (int p = 0; p < GSPL; ++p) v += gpart[((size_t)g * GSPL + p) * EMBD + c];
  s[c] = v;
  __syncthreads();
  if (c < 12) {
    float acc = 0.f;
    for (int k = 0; k < EMBD; ++k) acc += s[k] * Wn[k * 12 + c];
    float cv = gcnt[g];
    out[g * 12 + c] = (cv > 0.f) ? acc / cv + bn[c] : 0.f;
  }
}

// ---------------- launch ----------------

extern "C" void kernel_launch(void* const* d_in, const int* in_sizes, int n_in,
                              void* d_out, int out_size, void* d_ws, size_t ws_size,
                              hipStream_t stream) {
  const int*   x   = (const int*)d_in[0];
  const int*   src = (const int*)d_in[1];
  const int*   dst = (const int*)d_in[2];
  const float* e   = (const float*)d_in[3];
  const int*   gi  = (const int*)d_in[4];
  const float* emb = (const float*)d_in[5];
  const float* We  = (const float*)d_in[6];
  const float* be  = (const float*)d_in[7];
  const float* Wgx = (const float*)d_in[8];
  const float* Wgn = (const float*)d_in[9];
  const float* Wge = (const float*)d_in[10];
  const float* bg  = (const float*)d_in[11];
  const float* Wfx = (const float*)d_in[12];
  const float* Wfn = (const float*)d_in[13];
  const float* Wfe = (const float*)d_in[14];
  const float* bf  = (const float*)d_in[15];
  const float* Wn  = (const float*)d_in[16];
  const float* bn  = (const float*)d_in[17];
  float* out = (float*)d_out;

  char* ws = (char*)d_ws;
  size_t off = 0;
  auto alloc = [&](size_t bytes) {
    void* p = ws + off;
    off += (bytes + 255) & ~(size_t)255;
    return p;
  };
  float*           xn    = (float*)alloc((size_t)NN * EMBD * 4);
  __hip_bfloat16*  xnb   = (__hip_bfloat16*)alloc((size_t)NN * EMBD * 2);
  __hip_bfloat16*  Yb    = (__hip_bfloat16*)alloc((size_t)NN * 1024 * 2);
  float*           db_s  = (float*)alloc((size_t)NE * 4);
  int*             src_s = (int*)alloc((size_t)NE * 4);
  int*             cnt   = (int*)alloc((size_t)NN * 4);
  int*             roff  = (int*)alloc((size_t)(NN + 1) * 4);
  int*             curs  = (int*)alloc((size_t)NN * 4);
  float*           weff  = (float*)alloc((size_t)NL * 2 * RBFD * EMBD * 4);
  float*           beff  = (float*)alloc((size_t)NL * 2 * EMBD * 4);
  float*           tbl   = (float*)alloc((size_t)NL * (TBINS + 1) * 512 * 4);
  __hip_bfloat16*  WT    = (__hip_bfloat16*)alloc((size_t)NL * 4 * 256 * 256 * 2);
  float*           gpart = (float*)alloc((size_t)NG * GSPL * EMBD * 4);
  float*           gcnt  = (float*)alloc((size_t)NG * 4);
  (void)ws_size; (void)in_sizes; (void)n_in; (void)out_size;

  hipMemsetAsync(cnt, 0, (size_t)NN * 4, stream);

  k_embed<<<(NN * (EMBD / 4) + 255) / 256, 256, 0, stream>>>(x, emb, xn, xnb);
  k_wsmall<<<(NL * 2 * (RBFD + 1) * EMBD + 255) / 256, 256, 0, stream>>>(
      We, be, Wge, bg, Wfe, bf, weff, beff);
  k_table<<<(NL * (TBINS + 1) * 512 + 255) / 256, 256, 0, stream>>>(weff, beff, tbl);
  k_wprep<<<dim3(NL * 4, 16), 256, 0, stream>>>(Wgx, Wfx, Wgn, Wfn, WT);
  k_hist<<<(NE + 255) / 256, 256, 0, stream>>>(dst, cnt);
  k_scan<<<1, 1024, 0, stream>>>(cnt, roff, curs);
  k_scatter<<<(NE + 255) / 256, 256, 0, stream>>>(src, dst, e, curs, src_s, db_s);

  dim3 mmgrid((NN + 127) / 128, 8);
  for (int l = 0; l < NL; ++l) {
    k_nodemm<<<mmgrid, 256, 0, stream>>>(xnb, WT + (size_t)l * 4 * 65536, Yb);
    k_agg<<<NWAVE / 4, 256, 0, stream>>>(
        Yb, roff, src_s, db_s, tbl + (size_t)l * (TBINS + 1) * 512, xn, xnb);
  }
  k_gsum<<<dim3(NG, GSPL), 256, 0, stream>>>(xn, gi, gpart, gcnt);
  k_final<<<NG, 256, 0, stream>>>(gpart, gcnt, Wn, bn, out);
}

// Round 12
// 488.532 us; speedup vs baseline: 1.1609x; 1.0038x over previous
//
#include <hip/hip_runtime.h>
#include <hip/hip_bf16.h>
#include <math.h>

#define NN   20000
#define NE   200000
#define NG   128
#define EMBD 256
#define NL   4
#define RBFD 10
#define TBINS 1024      // lerp bins over d in [0,8]; table rows = TBINS+1
#define NWAVE 8192      // persistent waves in k_agg (2048 blocks x 4)
#define GSPL 8

typedef __attribute__((ext_vector_type(8))) short bf16x8;
typedef __attribute__((ext_vector_type(4))) float f32x4;

__device__ __forceinline__ f32x4 up4(uint2 u) {
  f32x4 r;
  r.x = __uint_as_float(u.x << 16);
  r.y = __uint_as_float(u.x & 0xffff0000u);
  r.z = __uint_as_float(u.y << 16);
  r.w = __uint_as_float(u.y & 0xffff0000u);
  return r;
}

__device__ __forceinline__ void gload16(const void* g, void* l) {
  __builtin_amdgcn_global_load_lds(
      (const __attribute__((address_space(1))) void*)g,
      (__attribute__((address_space(3))) void*)l, 16, 0, 0);
}

__device__ __forceinline__ unsigned short bfbits(float v) {
  __hip_bfloat16 h = __float2bfloat16(v);
  return *(unsigned short*)&h;
}

// ---------------- prep kernels ----------------

__global__ void k_embed(const int* __restrict__ x, const float* __restrict__ emb,
                        float* __restrict__ xn, __hip_bfloat16* __restrict__ xnb) {
  int idx = blockIdx.x * blockDim.x + threadIdx.x;   // float4 index
  if (idx >= NN * (EMBD / 4)) return;
  int n  = idx >> 6;
  int c4 = (idx & 63) << 2;
  float4 v = *(const float4*)(emb + (size_t)x[n] * EMBD + c4);
  *(float4*)(xn + (size_t)n * EMBD + c4) = v;
  __hip_bfloat16* xb = xnb + (size_t)n * EMBD + c4;
  xb[0] = __float2bfloat16(v.x); xb[1] = __float2bfloat16(v.y);
  xb[2] = __float2bfloat16(v.z); xb[3] = __float2bfloat16(v.w);
}

// weff[l][gf][k][c] = (We @ W*_e[l])[k][c];  beff[l][gf][c] = be @ W*_e[l] + b*[l]
__global__ void k_wsmall(const float* __restrict__ We, const float* __restrict__ be,
                         const float* __restrict__ Wge, const float* __restrict__ bg,
                         const float* __restrict__ Wfe, const float* __restrict__ bf,
                         float* __restrict__ weff, float* __restrict__ beff) {
  int tid = blockIdx.x * blockDim.x + threadIdx.x;
  const int WPER = RBFD * EMBD;   // 2560
  if (tid < NL * 2 * WPER) {
    int l  = tid / (2 * WPER);
    int r  = tid % (2 * WPER);
    int gf = r / WPER;
    int r2 = r % WPER;
    int k = r2 / EMBD, c = r2 % EMBD;
    const float* W = (gf == 0 ? Wge : Wfe) + (size_t)l * EMBD * EMBD;
    float s = 0.f;
    for (int j = 0; j < EMBD; ++j) s += We[k * EMBD + j] * W[(size_t)j * EMBD + c];
    weff[tid] = s;
  } else {
    int t2 = tid - NL * 2 * WPER;
    if (t2 >= NL * 2 * EMBD) return;
    int l  = t2 / (2 * EMBD);
    int r  = t2 % (2 * EMBD);
    int gf = r / EMBD, c = r % EMBD;
    const float* W = (gf == 0 ? Wge : Wfe) + (size_t)l * EMBD * EMBD;
    const float* b = (gf == 0 ? bg : bf) + (size_t)l * EMBD;
    float s = b[c];
    for (int j = 0; j < EMBD; ++j) s += be[j] * W[(size_t)j * EMBD + c];
    beff[t2] = s;
  }
}

// tbl[l][bin][t]: t<256 -> zg contribution of distance, t>=256 -> zf; bias folded in
__global__ void k_table(const float* __restrict__ weff, const float* __restrict__ beff,
                        float* __restrict__ tbl) {
  int idx = blockIdx.x * blockDim.x + threadIdx.x;
  if (idx >= NL * (TBINS + 1) * 512) return;
  int l = idx / ((TBINS + 1) * 512);
  int r = idx % ((TBINS + 1) * 512);
  int bin = r >> 9;
  int t = r & 511;
  int gf = t >> 8, c = t & 255;
  float d = (float)bin * (8.0f / (float)TBINS);
  const float* w = weff + ((size_t)(l * 2 + gf) * RBFD) * EMBD + c;
  float s = beff[(size_t)(l * 2 + gf) * EMBD + c];
  const float width = 8.0f / 9.0f;
  #pragma unroll
  for (int k = 0; k < RBFD; ++k) {
    float u = (d - (float)k * width) / width;
    s += __expf(-u * u) * w[(size_t)k * EMBD];
  }
  tbl[idx] = s;
}

// WT[l][q][c][k] = W_q[l][k][c] as bf16 (transposed, K-contiguous)
__global__ __launch_bounds__(256) void k_wprep(
    const float* __restrict__ Wgx, const float* __restrict__ Wfx,
    const float* __restrict__ Wgn, const float* __restrict__ Wfn,
    __hip_bfloat16* __restrict__ WT) {
  __shared__ float T[64][65];
  int lq = blockIdx.x; int l = lq >> 2, q = lq & 3;
  const float* W = (q == 0 ? Wgx : q == 1 ? Wfx : q == 2 ? Wgn : Wfn) + (size_t)l * 65536;
  int t = blockIdx.y;
  int k0 = (t & 3) * 64, c0 = (t >> 2) * 64;
  #pragma unroll
  for (int i = 0; i < 16; ++i) {
    int idx = threadIdx.x + i * 256;
    int r = idx >> 6, c = idx & 63;
    T[r][c] = W[(size_t)(k0 + r) * 256 + c0 + c];
  }
  __syncthreads();
  __hip_bfloat16* out = WT + ((size_t)lq * 256) * 256;
  #pragma unroll
  for (int i = 0; i < 16; ++i) {
    int idx = threadIdx.x + i * 256;
    int r = idx >> 6, c = idx & 63;
    out[(size_t)(c0 + r) * 256 + k0 + c] = __float2bfloat16(T[c][r]);
  }
}

// ---------------- CSR build ----------------

__global__ void k_hist(const int* __restrict__ dst, int* __restrict__ cnt) {
  int e = blockIdx.x * blockDim.x + threadIdx.x;
  if (e >= NE) return;
  atomicAdd(&cnt[dst[e]], 1);
}

__global__ __launch_bounds__(1024) void k_scan(const int* __restrict__ cnt,
                                               int* __restrict__ roff,
                                               int* __restrict__ cursor) {
  __shared__ int part[1024];
  const int t = threadIdx.x;
  const int CH = 20;
  int base = t * CH;
  int loc[CH];
  int s = 0;
  #pragma unroll
  for (int i = 0; i < CH; ++i) {
    int idx = base + i;
    int v = (idx < NN) ? cnt[idx] : 0;
    loc[i] = s;
    s += v;
  }
  part[t] = s;
  __syncthreads();
  for (int off = 1; off < 1024; off <<= 1) {
    int v = (t >= off) ? part[t - off] : 0;
    __syncthreads();
    part[t] += v;
    __syncthreads();
  }
  int chunkbase = (t == 0) ? 0 : part[t - 1];
  #pragma unroll
  for (int i = 0; i < CH; ++i) {
    int idx = base + i;
    if (idx < NN) {
      int v = chunkbase + loc[i];
      roff[idx] = v;
      cursor[idx] = v;
    }
  }
  if (t == 1023) roff[NN] = part[1023];
}

// scatter edges dst-sorted; store src and scaled distance (bin space)
__global__ void k_scatter(const int* __restrict__ src, const int* __restrict__ dst,
                          const float* __restrict__ edist,
                          int* __restrict__ cursor,
                          int* __restrict__ src_s, float* __restrict__ db_s) {
  int e = blockIdx.x * blockDim.x + threadIdx.x;
  if (e >= NE) return;
  int d = dst[e];
  int p = atomicAdd(&cursor[d], 1);
  src_s[p] = src[e];
  float dd = edist[e] * ((float)TBINS / 8.0f);
  db_s[p] = fminf(fmaxf(dd, 0.0f), (float)TBINS - 0.001f);
}

// ---------------- per-layer kernels ----------------

// Yb(20000 x 1024, bf16) = xnb @ [Wg_x | Wf_x | Wg_n | Wf_n]  (bf16 MFMA)
// BK=64, global_load_lds(16B) with pre-swizzled source, swapped-operand MFMA
// (D rows = channels) so epilogue stores are packed 8B.
__global__ __launch_bounds__(256) void k_nodemm(
    const __hip_bfloat16* __restrict__ xnb, const __hip_bfloat16* __restrict__ WTl,
    __hip_bfloat16* __restrict__ Yb) {
  __shared__ unsigned short As[128 * 64];   // [node][k-chunk swizzled], 16KB
  __shared__ unsigned short Bs[128 * 64];   // [channel][k-chunk swizzled], 16KB
  const int tid = threadIdx.x;
  const int lane = tid & 63;
  const int wave = tid >> 6;
  const int row0 = blockIdx.x << 7;          // node tile base
  const int col0 = blockIdx.y << 7;          // channel tile base (0..896)
  const int q = col0 >> 8;
  const int cb = col0 & 255;
  const unsigned short* xb = (const unsigned short*)xnb;
  const unsigned short* Wb = (const unsigned short*)WTl + ((size_t)q * 256 + cb) * 256;
  const int wnode = (wave >> 1) << 6;        // wave's node offset in tile
  const int wch   = (wave & 1) << 6;         // wave's channel offset in tile
  f32x4 acc[4][4] = {};                      // [channel frag][node frag]

  const int rd0 = (wave << 3) + (lane >> 3); // staging row, + j*32
  const int cd  = lane & 7;                  // staging dest chunk

  for (int k0 = 0; k0 < 256; k0 += 64) {
    #pragma unroll
    for (int j = 0; j < 4; ++j) {
      int rd = rd0 + j * 32;
      int cs = cd ^ (rd & 7);                // pre-swizzled source chunk
      int ga = row0 + rd; if (ga > NN - 1) ga = NN - 1;
      gload16(xb + (size_t)ga * 256 + k0 + cs * 8,
              (char*)As + (size_t)(j * 256 + wave * 64) * 16);
      gload16(Wb + (size_t)rd * 256 + k0 + cs * 8,
              (char*)Bs + (size_t)(j * 256 + wave * 64) * 16);
    }
    __syncthreads();
    const int rsel = lane & 15, ksl = lane >> 4;
    #pragma unroll
    for (int h = 0; h < 2; ++h) {
      const int c = h * 4 + ksl;
      bf16x8 xa[4], wf[4];
      #pragma unroll
      for (int nn = 0; nn < 4; ++nn) {
        int r = wnode + nn * 16 + rsel;
        xa[nn] = *(const bf16x8*)(&As[r * 64 + (c ^ (r & 7)) * 8]);
      }
      #pragma unroll
      for (int mc = 0; mc < 4; ++mc) {
        int r = wch + mc * 16 + rsel;
        wf[mc] = *(const bf16x8*)(&Bs[r * 64 + (c ^ (r & 7)) * 8]);
      }
      #pragma unroll
      for (int mc = 0; mc < 4; ++mc)
        #pragma unroll
        for (int nn = 0; nn < 4; ++nn)
          acc[mc][nn] = __builtin_amdgcn_mfma_f32_16x16x32_bf16(wf[mc], xa[nn], acc[mc][nn], 0, 0, 0);
    }
    __syncthreads();
  }

  // D: col = lane&15 -> node, row-quad = (lane>>4)*4 -> 4 consecutive channels
  const int nodesel = lane & 15;
  const int chq = (lane >> 4) << 2;
  #pragma unroll
  for (int mc = 0; mc < 4; ++mc) {
    #pragma unroll
    for (int nn = 0; nn < 4; ++nn) {
      int node = row0 + wnode + nn * 16 + nodesel;
      if (node < NN) {
        int ch = col0 + wch + mc * 16 + chq;
        ushort4 pk;
        pk.x = bfbits(acc[mc][nn][0]);
        pk.y = bfbits(acc[mc][nn][1]);
        pk.z = bfbits(acc[mc][nn][2]);
        pk.w = bfbits(acc[mc][nn][3]);
        *(ushort4*)((unsigned short*)Yb + (size_t)node * 1024 + ch) = pk;
      }
    }
  }
}

// msg contribution for one channel: sigmoid(zg) * softplus(zf)
// STABLE softplus: max(z,0) + ln(1 + e^{-|z|})
__device__ __forceinline__ float gate1(float zg, float zf) {
  float sg = __builtin_amdgcn_rcpf(1.0f + __expf(-zg));
  float sp = fmaxf(zf, 0.0f) + __logf(1.0f + __expf(-fabsf(zf)));
  return sg * sp;
}

// persistent grid-stride waves; per edge: 2 bf16 gathers + 4 table loads + lerp
__global__ __launch_bounds__(256, 8) void k_agg(
    const __hip_bfloat16* __restrict__ Yb, const int* __restrict__ roff,
    const int* __restrict__ src_s, const float* __restrict__ db_s,
    const float* __restrict__ tblL,
    float* __restrict__ xn, __hip_bfloat16* __restrict__ xnb) {
  const int wave = threadIdx.x >> 6, lane = threadIdx.x & 63;
  const int c4 = lane << 2;
  const int wid0 = blockIdx.x * 4 + wave;

  for (int n = wid0; n < NN; n += NWAVE) {
    const int jb   = __builtin_amdgcn_readfirstlane(roff[n]);
    const int jend = __builtin_amdgcn_readfirstlane(roff[n + 1]);
    const int deg = jend - jb;

    // dst terms (bias is folded into the table)
    const unsigned short* yrow = (const unsigned short*)Yb + (size_t)n * 1024 + c4;
    f32x4 bgv = up4(*(const uint2*)(yrow));
    f32x4 bfv = up4(*(const uint2*)(yrow + 256));

    f32x4 m4 = {};
    if (deg > 0) {
      const int dcap = deg < 64 ? deg : 64;
      int sv = 0; int bv = 0; int fv = 0;
      if (lane < dcap) {
        sv = src_s[jb + lane];
        float db = db_s[jb + lane];
        int b = (int)db;
        bv = b;
        fv = __float_as_int(db - (float)b);
      }
      const unsigned short* Ysrc = (const unsigned short*)Yb + c4 + 512;
      for (int i = 0; i < dcap; ++i) {
        int sn = __builtin_amdgcn_readlane(sv, i);
        int bn = __builtin_amdgcn_readlane(bv, i);
        float fr = __int_as_float(__builtin_amdgcn_readlane(fv, i));
        const unsigned short* ys = Ysrc + (size_t)sn * 1024;
        uint2 pa = *(const uint2*)(ys);
        uint2 pf = *(const uint2*)(ys + 256);
        const float* tp = tblL + (size_t)bn * 512 + c4;
        f32x4 t0g = *(const f32x4*)(tp);
        f32x4 t0f = *(const f32x4*)(tp + 256);
        f32x4 t1g = *(const f32x4*)(tp + 512);
        f32x4 t1f = *(const f32x4*)(tp + 768);
        f32x4 zg = bgv + up4(pa) + t0g + fr * (t1g - t0g);
        f32x4 zf = bfv + up4(pf) + t0f + fr * (t1f - t0f);
        m4.x += gate1(zg.x, zf.x);
        m4.y += gate1(zg.y, zf.y);
        m4.z += gate1(zg.z, zf.z);
        m4.w += gate1(zg.w, zf.w);
      }
      // rare tail (deg > 64): uniform scalar loads
      for (int i = 64; i < deg; ++i) {
        int sn = src_s[jb + i];
        float db = db_s[jb + i];
        int bn = (int)db;
        float fr = db - (float)bn;
        const unsigned short* ys = Ysrc + (size_t)sn * 1024;
        uint2 pa = *(const uint2*)(ys);
        uint2 pf = *(const uint2*)(ys + 256);
        const float* tp = tblL + (size_t)bn * 512 + c4;
        f32x4 t0g = *(const f32x4*)(tp);
        f32x4 t0f = *(const f32x4*)(tp + 256);
        f32x4 t1g = *(const f32x4*)(tp + 512);
        f32x4 t1f = *(const f32x4*)(tp + 768);
        f32x4 zg = bgv + up4(pa) + t0g + fr * (t1g - t0g);
        f32x4 zf = bfv + up4(pf) + t0f + fr * (t1f - t0f);
        m4.x += gate1(zg.x, zf.x);
        m4.y += gate1(zg.y, zf.y);
        m4.z += gate1(zg.z, zf.z);
        m4.w += gate1(zg.w, zf.w);
      }
    }
    float4 xv = *(const float4*)(xn + (size_t)n * EMBD + c4);
    xv.x += m4.x; xv.y += m4.y; xv.z += m4.z; xv.w += m4.w;
    *(float4*)(xn + (size_t)n * EMBD + c4) = xv;
    __hip_bfloat16* xbp = xnb + (size_t)n * EMBD + c4;
    xbp[0] = __float2bfloat16(xv.x); xbp[1] = __float2bfloat16(xv.y);
    xbp[2] = __float2bfloat16(xv.z); xbp[3] = __float2bfloat16(xv.w);
  }
}

// ---------------- readout (atomic-free, split partials) ----------------

__global__ __launch_bounds__(256) void k_gsum(
    const float* __restrict__ xn, const int* __restrict__ gi,
    float* __restrict__ gpart, float* __restrict__ gcnt) {
  const int g = blockIdx.x, p = blockIdx.y;
  int lo = 0, hi = NN;
  while (lo < hi) { int m = (lo + hi) >> 1; if (gi[m] < g) lo = m + 1; else hi = m; }
  int lo2 = lo, hi2 = NN;
  while (lo2 < hi2) { int m = (lo2 + hi2) >> 1; if (gi[m] < g + 1) lo2 = m + 1; else hi2 = m; }
  const int cntv = lo2 - lo;
  const int r0 = lo + (cntv * p) / GSPL;
  const int r1 = lo + (cntv * (p + 1)) / GSPL;
  const int c = threadIdx.x;
  float acc = 0.f;
  for (int r = r0; r < r1; ++r) acc += xn[(size_t)r * EMBD + c];
  gpart[((size_t)g * GSPL + p) * EMBD + c] = acc;
  if (p == 0 && c == 0) gcnt[g] = (float)cntv;
}

__global__ __launch_bounds__(256) void k_final(
    const float* __restrict__ gpart, const float* __restrict__ gcnt,
    const float* __restrict__ Wn, const float* __restrict__ bn,
    float* __restrict__ out) {
  __shared__ float s[EMBD];
  const int g = blockIdx.x;
  const int c = threadIdx.x;
  float v = 0.f;
  #pragma unroll
  for (int p = 0; p < GSPL; ++p) v += gpart[((size_t)g * GSPL + p) * EMBD + c];
  s[c] = v;
  __syncthreads();
  if (c < 12) {
    float acc = 0.f;
    for (int k = 0; k < EMBD; ++k) acc += s[k] * Wn[k * 12 + c];
    float cv = gcnt[g];
    out[g * 12 + c] = (cv > 0.f) ? acc / cv + bn[c] : 0.f;
  }
}

// ---------------- launch ----------------

extern "C" void kernel_launch(void* const* d_in, const int* in_sizes, int n_in,
                              void* d_out, int out_size, void* d_ws, size_t ws_size,
                              hipStream_t stream) {
  const int*   x   = (const int*)d_in[0];
  const int*   src = (const int*)d_in[1];
  const int*   dst = (const int*)d_in[2];
  const float* e   = (const float*)d_in[3];
  const int*   gi  = (const int*)d_in[4];
  const float* emb = (const float*)d_in[5];
  const float* We  = (const float*)d_in[6];
  const float* be  = (const float*)d_in[7];
  const float* Wgx = (const float*)d_in[8];
  const float* Wgn = (const float*)d_in[9];
  const float* Wge = (const float*)d_in[10];
  const float* bg  = (const float*)d_in[11];
  const float* Wfx = (const float*)d_in[12];
  const float* Wfn = (const float*)d_in[13];
  const float* Wfe = (const float*)d_in[14];
  const float* bf  = (const float*)d_in[15];
  const float* Wn  = (const float*)d_in[16];
  const float* bn  = (const float*)d_in[17];
  float* out = (float*)d_out;

  char* ws = (char*)d_ws;
  size_t off = 0;
  auto alloc = [&](size_t bytes) {
    void* p = ws + off;
    off += (bytes + 255) & ~(size_t)255;
    return p;
  };
  float*           xn    = (float*)alloc((size_t)NN * EMBD * 4);
  __hip_bfloat16*  xnb   = (__hip_bfloat16*)alloc((size_t)NN * EMBD * 2);
  __hip_bfloat16*  Yb    = (__hip_bfloat16*)alloc((size_t)NN * 1024 * 2);
  float*           db_s  = (float*)alloc((size_t)NE * 4);
  int*             src_s = (int*)alloc((size_t)NE * 4);
  int*             cnt   = (int*)alloc((size_t)NN * 4);
  int*             roff  = (int*)alloc((size_t)(NN + 1) * 4);
  int*             curs  = (int*)alloc((size_t)NN * 4);
  float*           weff  = (float*)alloc((size_t)NL * 2 * RBFD * EMBD * 4);
  float*           beff  = (float*)alloc((size_t)NL * 2 * EMBD * 4);
  float*           tbl   = (float*)alloc((size_t)NL * (TBINS + 1) * 512 * 4);
  __hip_bfloat16*  WT    = (__hip_bfloat16*)alloc((size_t)NL * 4 * 256 * 256 * 2);
  float*           gpart = (float*)alloc((size_t)NG * GSPL * EMBD * 4);
  float*           gcnt  = (float*)alloc((size_t)NG * 4);
  (void)ws_size; (void)in_sizes; (void)n_in; (void)out_size;

  hipMemsetAsync(cnt, 0, (size_t)NN * 4, stream);

  k_embed<<<(NN * (EMBD / 4) + 255) / 256, 256, 0, stream>>>(x, emb, xn, xnb);
  k_wsmall<<<(NL * 2 * (RBFD + 1) * EMBD + 255) / 256, 256, 0, stream>>>(
      We, be, Wge, bg, Wfe, bf, weff, beff);
  k_table<<<(NL * (TBINS + 1) * 512 + 255) / 256, 256, 0, stream>>>(weff, beff, tbl);
  k_wprep<<<dim3(NL * 4, 16), 256, 0, stream>>>(Wgx, Wfx, Wgn, Wfn, WT);
  k_hist<<<(NE + 255) / 256, 256, 0, stream>>>(dst, cnt);
  k_scan<<<1, 1024, 0, stream>>>(cnt, roff, curs);
  k_scatter<<<(NE + 255) / 256, 256, 0, stream>>>(src, dst, e, curs, src_s, db_s);

  dim3 mmgrid((NN + 127) / 128, 8);
  for (int l = 0; l < NL; ++l) {
    k_nodemm<<<mmgrid, 256, 0, stream>>>(xnb, WT + (size_t)l * 4 * 65536, Yb);
    k_agg<<<NWAVE / 4, 256, 0, stream>>>(
        Yb, roff, src_s, db_s, tbl + (size_t)l * (TBINS + 1) * 512, xn, xnb);
  }
  k_gsum<<<dim3(NG, GSPL), 256, 0, stream>>>(xn, gi, gpart, gcnt);
  k_final<<<NG, 256, 0, stream>>>(gpart, gcnt, Wn, bn, out);
}